// Round 1
// baseline (361.106 us; speedup 1.0000x reference)
//
#include <hip/hip_runtime.h>
#include <math.h>

#define LL 256
#define BB 128
#define EDIM 1024
#define HDIM 1024
#define VOCAB 32000

// workspace layout (float offsets)
#define WS_EACT   0           // 64000 floats (VOCAB*2)
#define WS_DELTA  64000       // 256
#define WS_DIFFB  64256       // 256
#define WS_TOKF   64512       // 256 ints
#define WS_FHID   64768       // 256*1024
#define WS_PART   326912      // 16*128*1024

// K1: E_act[v][a] = emb[v,:] . W_act[:,a]   (streams emb once: 131 MB)
extern "C" __global__ __launch_bounds__(256)
void k_eact(const float* __restrict__ emb, const float* __restrict__ Wact,
            float* __restrict__ Eact) {
  int lane = threadIdx.x & 63;
  int wave = threadIdx.x >> 6;
  int v = blockIdx.x * 4 + wave;
  const float4* row = (const float4*)(emb + (size_t)v * EDIM);
  const float4* w4 = (const float4*)Wact;   // w4[j] = {w0[2j],w1[2j],w0[2j+1],w1[2j+1]}
  float a0 = 0.f, a1 = 0.f;
#pragma unroll
  for (int it = 0; it < 4; ++it) {
    int i = lane + it * 64;        // float4 index: elements 4i..4i+3
    float4 x = row[i];
    float4 wa = w4[2 * i];
    float4 wb = w4[2 * i + 1];
    a0 = fmaf(x.x, wa.x, a0); a0 = fmaf(x.y, wa.z, a0);
    a0 = fmaf(x.z, wb.x, a0); a0 = fmaf(x.w, wb.z, a0);
    a1 = fmaf(x.x, wa.y, a1); a1 = fmaf(x.y, wa.w, a1);
    a1 = fmaf(x.z, wb.y, a1); a1 = fmaf(x.w, wb.w, a1);
  }
#pragma unroll
  for (int off = 32; off; off >>= 1) {
    a0 += __shfl_down(a0, off, 64);
    a1 += __shfl_down(a1, off, 64);
  }
  if (lane == 0) { Eact[2 * v] = a0; Eact[2 * v + 1] = a1; }
}

// K2: per (seq s, batch b): lens, Ts, ragged softmax stats, final token
extern "C" __global__ __launch_bounds__(256)
void k_stats(const int* __restrict__ seq1, const int* __restrict__ seq2,
             const float* __restrict__ Eact, const float* __restrict__ b_act,
             float* __restrict__ delta, float* __restrict__ diffb,
             int* __restrict__ tokf) {
  int bx = blockIdx.x;
  int s = bx >> 7, b = bx & 127;
  const int* seq = s ? seq2 : seq1;
  int tid = threadIdx.x;
  __shared__ int col[LL];
  __shared__ int redi[256];
  __shared__ float redf[256];
  col[tid] = seq[tid * BB + b];
  __syncthreads();
  redi[tid] = (col[tid] == 0) ? 1 : 0;
  __syncthreads();
  for (int off = 128; off; off >>= 1) {
    if (tid < off) redi[tid] += redi[tid + off];
    __syncthreads();
  }
  int lens = LL - redi[0] - 1;
  int Ts = 2 * lens - 1;
  float ba = b_act[0] - b_act[1];
  float sp = 0.f, spp = 0.f, sq = 0.f;
  for (int t = tid; t < Ts; t += 256) {
    int tok = (t < LL) ? col[t] : col[t - LL];
    float2 e = ((const float2*)Eact)[tok];
    float d = e.x - e.y + ba;
    float p0 = 1.0f / (1.0f + expf(-d));
    float p1 = 1.0f - p0;
    sp += p0; spp += p1;
    float dd = p0 - p1;
    sq = fmaf(dd, dd, sq);
  }
  redf[tid] = sp; __syncthreads();
  for (int off = 128; off; off >>= 1) { if (tid < off) redf[tid] += redf[tid + off]; __syncthreads(); }
  float tsp = redf[0]; __syncthreads();
  redf[tid] = spp; __syncthreads();
  for (int off = 128; off; off >>= 1) { if (tid < off) redf[tid] += redf[tid + off]; __syncthreads(); }
  float tspp = redf[0]; __syncthreads();
  redf[tid] = sq; __syncthreads();
  for (int off = 128; off; off >>= 1) { if (tid < off) redf[tid] += redf[tid + off]; __syncthreads(); }
  float tsq = redf[0];
  if (tid == 0) {
    float Tf = (float)Ts;
    delta[bx] = (tsp - tspp - 1.0f) / Tf;   // sum_push - sum_pop
    diffb[bx] = sqrtf(tsq) / Tf;
    int tt = Ts - 1;
    tokf[bx] = (tt < LL) ? col[tt] : col[tt - LL];
  }
}

// K3: dis_s = ||delta_s||/B ; diff_s = sum(diffb_s)/B
extern "C" __global__ __launch_bounds__(256)
void k_final(const float* __restrict__ delta, const float* __restrict__ diffb,
             float* __restrict__ out) {
  __shared__ float red[256];
  int tid = threadIdx.x;
  for (int s = 0; s < 2; ++s) {
    float v = 0.f, w = 0.f;
    if (tid < BB) { float d = delta[s * BB + tid]; v = d * d; w = diffb[s * BB + tid]; }
    red[tid] = v; __syncthreads();
    for (int off = 128; off; off >>= 1) { if (tid < off) red[tid] += red[tid + off]; __syncthreads(); }
    if (tid == 0) out[384 + s] = sqrtf(red[0]) / (float)BB;
    __syncthreads();
    red[tid] = w; __syncthreads();
    for (int off = 128; off; off >>= 1) { if (tid < off) red[tid] += red[tid + off]; __syncthreads(); }
    if (tid == 0) out[386 + s] = red[0] / (float)BB;
    __syncthreads();
  }
}

// K4: fhid[256][1024] = tanh(emb[tokf] @ W_top + b_top)
// grid (16 colblocks of 64, 16 rowblocks of 16); thread = 4 cols x 1 row
extern "C" __global__ __launch_bounds__(256)
void k_fhid(const float* __restrict__ emb, const float* __restrict__ Wtop,
            const float* __restrict__ btop, const int* __restrict__ tokf,
            float* __restrict__ fhid) {
  int cb = blockIdx.x;
  int rb = blockIdx.y;
  int tid = threadIdx.x;
  int cg = tid & 15;          // 16 col groups of 4 cols
  int rgr = tid >> 4;         // 16 rows
  int c0 = cb * 64 + cg * 4;
  __shared__ float a_sh[16 * 256];
  __shared__ int stok[16];
  if (tid < 16) stok[tid] = tokf[rb * 16 + tid];
  __syncthreads();
  float4 acc = make_float4(0.f, 0.f, 0.f, 0.f);
  for (int ch = 0; ch < 4; ++ch) {
    __syncthreads();
    for (int idx = tid; idx < 16 * 64; idx += 256) {
      int r = idx >> 6, e4 = idx & 63;
      ((float4*)a_sh)[r * 64 + e4] =
          ((const float4*)(emb + (size_t)stok[r] * EDIM + ch * 256))[e4];
    }
    __syncthreads();
    for (int kk = 0; kk < 256; kk += 4) {
      float4 a = *(const float4*)&a_sh[rgr * 256 + kk];
      int kg = ch * 256 + kk;
      float4 w0 = *(const float4*)&Wtop[(size_t)(kg + 0) * HDIM + c0];
      float4 w1 = *(const float4*)&Wtop[(size_t)(kg + 1) * HDIM + c0];
      float4 w2 = *(const float4*)&Wtop[(size_t)(kg + 2) * HDIM + c0];
      float4 w3 = *(const float4*)&Wtop[(size_t)(kg + 3) * HDIM + c0];
      acc.x = fmaf(a.x, w0.x, acc.x); acc.y = fmaf(a.x, w0.y, acc.y);
      acc.z = fmaf(a.x, w0.z, acc.z); acc.w = fmaf(a.x, w0.w, acc.w);
      acc.x = fmaf(a.y, w1.x, acc.x); acc.y = fmaf(a.y, w1.y, acc.y);
      acc.z = fmaf(a.y, w1.z, acc.z); acc.w = fmaf(a.y, w1.w, acc.w);
      acc.x = fmaf(a.z, w2.x, acc.x); acc.y = fmaf(a.z, w2.y, acc.y);
      acc.z = fmaf(a.z, w2.z, acc.z); acc.w = fmaf(a.z, w2.w, acc.w);
      acc.x = fmaf(a.w, w3.x, acc.x); acc.y = fmaf(a.w, w3.y, acc.y);
      acc.z = fmaf(a.w, w3.z, acc.z); acc.w = fmaf(a.w, w3.w, acc.w);
    }
  }
  int row = rb * 16 + rgr;
  float4 bt = *(const float4*)&btop[c0];
  float4 o;
  o.x = tanhf(acc.x + bt.x);
  o.y = tanhf(acc.y + bt.y);
  o.z = tanhf(acc.z + bt.z);
  o.w = tanhf(acc.w + bt.w);
  *(float4*)&fhid[(size_t)row * HDIM + c0] = o;
}

// K5a: partial[ks][128][1024] : K-split GEMM  u(128x4096) @ W1(4096x1024)
// grid (16 colblocks of 64, 16 ksplits of 256); thread = 8 rows x 4 cols
extern "C" __global__ __launch_bounds__(256)
void k_part(const float* __restrict__ fhid, const float* __restrict__ W1,
            float* __restrict__ part) {
  int cb = blockIdx.x;
  int ksb = blockIdx.y;
  int tid = threadIdx.x;
  int cg = tid & 15;          // 4 cols
  int rgr = tid >> 4;         // 8 rows: rgr*8..+7
  int c0 = cb * 64 + cg * 4;
  int k0 = ksb * 256;
  int seg = k0 >> 10;         // u segment (uniform per block)
  int fbase = k0 & 1023;
  __shared__ float u_sh[128 * 64];
  float4 acc[8];
#pragma unroll
  for (int r = 0; r < 8; ++r) acc[r] = make_float4(0.f, 0.f, 0.f, 0.f);
  for (int ch = 0; ch < 4; ++ch) {
    __syncthreads();
    int fb = fbase + ch * 64;
    for (int idx = tid; idx < 128 * 64; idx += 256) {
      int row = idx >> 6, f = idx & 63;
      float u;
      if (seg == 0) {
        u = fhid[(size_t)row * 1024 + fb + f];
      } else if (seg == 1) {
        u = fhid[(size_t)(128 + row) * 1024 + fb + f];
      } else {
        float f1 = fhid[(size_t)row * 1024 + fb + f];
        float f2 = fhid[(size_t)(128 + row) * 1024 + fb + f];
        u = (seg == 2) ? fabsf(f1 - f2) : f1 * f2;
      }
      u_sh[idx] = u;
    }
    __syncthreads();
    for (int kk = 0; kk < 64; kk += 4) {
      int kg = k0 + ch * 64 + kk;
      float4 w0 = *(const float4*)&W1[(size_t)(kg + 0) * HDIM + c0];
      float4 w1 = *(const float4*)&W1[(size_t)(kg + 1) * HDIM + c0];
      float4 w2 = *(const float4*)&W1[(size_t)(kg + 2) * HDIM + c0];
      float4 w3 = *(const float4*)&W1[(size_t)(kg + 3) * HDIM + c0];
#pragma unroll
      for (int r = 0; r < 8; ++r) {
        float4 a = *(const float4*)&u_sh[(rgr * 8 + r) * 64 + kk];
        acc[r].x = fmaf(a.x, w0.x, acc[r].x); acc[r].y = fmaf(a.x, w0.y, acc[r].y);
        acc[r].z = fmaf(a.x, w0.z, acc[r].z); acc[r].w = fmaf(a.x, w0.w, acc[r].w);
        acc[r].x = fmaf(a.y, w1.x, acc[r].x); acc[r].y = fmaf(a.y, w1.y, acc[r].y);
        acc[r].z = fmaf(a.y, w1.z, acc[r].z); acc[r].w = fmaf(a.y, w1.w, acc[r].w);
        acc[r].x = fmaf(a.z, w2.x, acc[r].x); acc[r].y = fmaf(a.z, w2.y, acc[r].y);
        acc[r].z = fmaf(a.z, w2.z, acc[r].z); acc[r].w = fmaf(a.z, w2.w, acc[r].w);
        acc[r].x = fmaf(a.w, w3.x, acc[r].x); acc[r].y = fmaf(a.w, w3.y, acc[r].y);
        acc[r].z = fmaf(a.w, w3.z, acc[r].z); acc[r].w = fmaf(a.w, w3.w, acc[r].w);
      }
    }
  }
#pragma unroll
  for (int r = 0; r < 8; ++r) {
    int row = rgr * 8 + r;
    *(float4*)&part[((size_t)ksb * 128 + row) * 1024 + c0] = acc[r];
  }
}

// K5c: out[b] = relu(sum_ks partial + b1) @ W2 + b2
extern "C" __global__ __launch_bounds__(256)
void k_clf(const float* __restrict__ part, const float* __restrict__ b1,
           const float* __restrict__ W2, const float* __restrict__ b2,
           float* __restrict__ out) {
  int b = blockIdx.x;
  int tid = threadIdx.x;
  float a0 = 0.f, a1 = 0.f, a2 = 0.f;
  for (int k = tid; k < 1024; k += 256) {
    float p = b1[k];
#pragma unroll
    for (int ks = 0; ks < 16; ++ks)
      p += part[((size_t)ks * 128 + b) * 1024 + k];
    p = fmaxf(p, 0.f);
    a0 = fmaf(p, W2[k * 3 + 0], a0);
    a1 = fmaf(p, W2[k * 3 + 1], a1);
    a2 = fmaf(p, W2[k * 3 + 2], a2);
  }
  __shared__ float red[256];
  red[tid] = a0; __syncthreads();
  for (int off = 128; off; off >>= 1) { if (tid < off) red[tid] += red[tid + off]; __syncthreads(); }
  if (tid == 0) out[b * 3 + 0] = red[0] + b2[0];
  __syncthreads();
  red[tid] = a1; __syncthreads();
  for (int off = 128; off; off >>= 1) { if (tid < off) red[tid] += red[tid + off]; __syncthreads(); }
  if (tid == 0) out[b * 3 + 1] = red[0] + b2[1];
  __syncthreads();
  red[tid] = a2; __syncthreads();
  for (int off = 128; off; off >>= 1) { if (tid < off) red[tid] += red[tid + off]; __syncthreads(); }
  if (tid == 0) out[b * 3 + 2] = red[0] + b2[2];
}

extern "C" void kernel_launch(void* const* d_in, const int* in_sizes, int n_in,
                              void* d_out, int out_size, void* d_ws, size_t ws_size,
                              hipStream_t stream) {
  const int*   seq1  = (const int*)  d_in[0];
  const int*   seq2  = (const int*)  d_in[1];
  const float* emb   = (const float*)d_in[2];
  const float* W_top = (const float*)d_in[3];
  const float* b_top = (const float*)d_in[4];
  const float* W_act = (const float*)d_in[5];
  const float* b_act = (const float*)d_in[6];
  const float* W1    = (const float*)d_in[7];
  const float* b1    = (const float*)d_in[8];
  const float* W2    = (const float*)d_in[9];
  const float* b2    = (const float*)d_in[10];
  float* out = (float*)d_out;
  float* ws  = (float*)d_ws;

  float* Eact  = ws + WS_EACT;
  float* delta = ws + WS_DELTA;
  float* diffb = ws + WS_DIFFB;
  int*   tokf  = (int*)(ws + WS_TOKF);
  float* fhid  = ws + WS_FHID;
  float* part  = ws + WS_PART;

  hipLaunchKernelGGL(k_eact,  dim3(VOCAB / 4), dim3(256), 0, stream, emb, W_act, Eact);
  hipLaunchKernelGGL(k_stats, dim3(256),       dim3(256), 0, stream, seq1, seq2, Eact, b_act, delta, diffb, tokf);
  hipLaunchKernelGGL(k_final, dim3(1),         dim3(256), 0, stream, delta, diffb, out);
  hipLaunchKernelGGL(k_fhid,  dim3(16, 16),    dim3(256), 0, stream, emb, W_top, b_top, tokf, fhid);
  hipLaunchKernelGGL(k_part,  dim3(16, 16),    dim3(256), 0, stream, fhid, W1, part);
  hipLaunchKernelGGL(k_clf,   dim3(128),       dim3(256), 0, stream, part, b1, W2, b2, out);
}

// Round 2
// 280.691 us; speedup vs baseline: 1.2865x; 1.2865x over previous
//
#include <hip/hip_runtime.h>
#include <math.h>

#define LL 256
#define BB 128
#define EDIM 1024
#define HDIM 1024
#define VOCAB 32000

// workspace layout (float offsets)
#define WS_EACT   0           // 64000
#define WS_DELTA  64000       // 256
#define WS_DIFFB  64256       // 256
#define WS_TOKF   64512       // 256 ints
#define WS_FHID   64768       // 256*1024 = 262144
#define WS_BIG    326912      // fpart / part union (2.1M or 4.2M floats)

__device__ __forceinline__ void fma4(float4& acc, float s, const float4& w) {
  acc.x = fmaf(s, w.x, acc.x); acc.y = fmaf(s, w.y, acc.y);
  acc.z = fmaf(s, w.z, acc.z); acc.w = fmaf(s, w.w, acc.w);
}

// K1: E_act[v][a] = emb[v,:] . W_act[:,a]  (streams emb once: 131 MB)
// Block 0 also zeroes out[0..383] for k_clf's atomics (k_clf runs much later).
extern "C" __global__ __launch_bounds__(256)
void k_eact(const float* __restrict__ emb, const float* __restrict__ Wact,
            float* __restrict__ Eact, float* __restrict__ out) {
  if (blockIdx.x == 0 && threadIdx.x < 96)
    ((float4*)out)[threadIdx.x] = make_float4(0.f, 0.f, 0.f, 0.f);
  int lane = threadIdx.x & 63;
  int wave = threadIdx.x >> 6;
  int v = blockIdx.x * 4 + wave;
  const float4* row = (const float4*)(emb + (size_t)v * EDIM);
  const float4* w4 = (const float4*)Wact;
  float a0 = 0.f, a1 = 0.f;
#pragma unroll
  for (int it = 0; it < 4; ++it) {
    int i = lane + it * 64;
    float4 x = row[i];
    float4 wa = w4[2 * i];
    float4 wb = w4[2 * i + 1];
    a0 = fmaf(x.x, wa.x, a0); a0 = fmaf(x.y, wa.z, a0);
    a0 = fmaf(x.z, wb.x, a0); a0 = fmaf(x.w, wb.z, a0);
    a1 = fmaf(x.x, wa.y, a1); a1 = fmaf(x.y, wa.w, a1);
    a1 = fmaf(x.z, wb.y, a1); a1 = fmaf(x.w, wb.w, a1);
  }
#pragma unroll
  for (int off = 32; off; off >>= 1) {
    a0 += __shfl_down(a0, off, 64);
    a1 += __shfl_down(a1, off, 64);
  }
  if (lane == 0) { Eact[2 * v] = a0; Eact[2 * v + 1] = a1; }
}

// K2: per (seq s, batch b): lens, Ts, ragged 2-class-softmax stats, final token
extern "C" __global__ __launch_bounds__(256)
void k_stats(const int* __restrict__ seq1, const int* __restrict__ seq2,
             const float* __restrict__ Eact, const float* __restrict__ b_act,
             float* __restrict__ delta, float* __restrict__ diffb,
             int* __restrict__ tokf) {
  int bx = blockIdx.x;
  int s = bx >> 7, b = bx & 127;
  const int* seq = s ? seq2 : seq1;
  int tid = threadIdx.x;
  __shared__ int col[LL];
  __shared__ int redi[256];
  __shared__ float redf[256];
  col[tid] = seq[tid * BB + b];
  __syncthreads();
  redi[tid] = (col[tid] == 0) ? 1 : 0;
  __syncthreads();
  for (int off = 128; off; off >>= 1) {
    if (tid < off) redi[tid] += redi[tid + off];
    __syncthreads();
  }
  int lens = LL - redi[0] - 1;
  int Ts = 2 * lens - 1;
  float ba = b_act[0] - b_act[1];
  float sp = 0.f, spp = 0.f, sq = 0.f;
  for (int t = tid; t < Ts; t += 256) {
    int tok = (t < LL) ? col[t] : col[t - LL];
    float2 e = ((const float2*)Eact)[tok];
    float d = e.x - e.y + ba;
    float p0 = 1.0f / (1.0f + expf(-d));
    float p1 = 1.0f - p0;
    sp += p0; spp += p1;
    float dd = p0 - p1;
    sq = fmaf(dd, dd, sq);
  }
  redf[tid] = sp; __syncthreads();
  for (int off = 128; off; off >>= 1) { if (tid < off) redf[tid] += redf[tid + off]; __syncthreads(); }
  float tsp = redf[0]; __syncthreads();
  redf[tid] = spp; __syncthreads();
  for (int off = 128; off; off >>= 1) { if (tid < off) redf[tid] += redf[tid + off]; __syncthreads(); }
  float tspp = redf[0]; __syncthreads();
  redf[tid] = sq; __syncthreads();
  for (int off = 128; off; off >>= 1) { if (tid < off) redf[tid] += redf[tid + off]; __syncthreads(); }
  float tsq = redf[0];
  if (tid == 0) {
    float Tf = (float)Ts;
    delta[bx] = (tsp - tspp - 1.0f) / Tf;
    diffb[bx] = sqrtf(tsq) / Tf;
    int tt = Ts - 1;
    tokf[bx] = (tt < LL) ? col[tt] : col[tt - LL];
  }
}

// K3: dis_s = ||delta_s||/B ; diff_s = sum(diffb_s)/B  (direct writes, not atomics)
extern "C" __global__ __launch_bounds__(256)
void k_final(const float* __restrict__ delta, const float* __restrict__ diffb,
             float* __restrict__ out) {
  __shared__ float red[256];
  int tid = threadIdx.x;
  for (int s = 0; s < 2; ++s) {
    float v = 0.f, w = 0.f;
    if (tid < BB) { float d = delta[s * BB + tid]; v = d * d; w = diffb[s * BB + tid]; }
    red[tid] = v; __syncthreads();
    for (int off = 128; off; off >>= 1) { if (tid < off) red[tid] += red[tid + off]; __syncthreads(); }
    if (tid == 0) out[384 + s] = sqrtf(red[0]) / (float)BB;
    __syncthreads();
    red[tid] = w; __syncthreads();
    for (int off = 128; off; off >>= 1) { if (tid < off) red[tid] += red[tid + off]; __syncthreads(); }
    if (tid == 0) out[386 + s] = red[0] / (float)BB;
    __syncthreads();
  }
}

// K4a: K-split GEMM partials for fhid: fpart[ks][256][1024] = emb[tokf] @ W_top
// grid (16 cb of 64 cols, 2 rb of 128 rows, nksf ksplits); thread = 4 cols x 8 rows
extern "C" __global__ __launch_bounds__(256)
void k_fpart(const float* __restrict__ emb, const float* __restrict__ Wtop,
             const int* __restrict__ tokf, float* __restrict__ fpart, int nch) {
  int cb = blockIdx.x, rb = blockIdx.y, ks = blockIdx.z;
  int tid = threadIdx.x;
  int cg = tid & 15, rgr = tid >> 4;
  int c0 = cb * 64 + cg * 4;
  int kbase = ks * nch * 64;
  __shared__ float ash[128 * 64];   // [row][k] 32 KB
  __shared__ int stok[128];
  if (tid < 128) stok[tid] = tokf[rb * 128 + tid];
  float4 acc[8];
#pragma unroll
  for (int r = 0; r < 8; ++r) acc[r] = make_float4(0.f, 0.f, 0.f, 0.f);
  for (int ch = 0; ch < nch; ++ch) {
    int kg = kbase + ch * 64;
    __syncthreads();
    for (int idx = tid; idx < 128 * 16; idx += 256) {
      int r = idx >> 4, q = idx & 15;
      ((float4*)ash)[idx] = ((const float4*)(emb + (size_t)stok[r] * EDIM + kg))[q];
    }
    __syncthreads();
    const float* Wp = Wtop + (size_t)kg * HDIM + c0;
    float4 w[4];
#pragma unroll
    for (int j = 0; j < 4; ++j) w[j] = *(const float4*)(Wp + (size_t)j * HDIM);
#pragma unroll
    for (int kk = 0; kk < 64; kk += 4) {
      float4 wn[4];
      if (kk + 4 < 64) {
#pragma unroll
        for (int j = 0; j < 4; ++j) wn[j] = *(const float4*)(Wp + (size_t)(kk + 4 + j) * HDIM);
      }
#pragma unroll
      for (int r = 0; r < 8; ++r) {
        float4 a = *(const float4*)&ash[(rgr * 8 + r) * 64 + kk];
        fma4(acc[r], a.x, w[0]); fma4(acc[r], a.y, w[1]);
        fma4(acc[r], a.z, w[2]); fma4(acc[r], a.w, w[3]);
      }
#pragma unroll
      for (int j = 0; j < 4; ++j) w[j] = wn[j];
    }
  }
  float* dst = fpart + ((size_t)ks * 256 + rb * 128 + rgr * 8) * HDIM + c0;
#pragma unroll
  for (int r = 0; r < 8; ++r)
    *(float4*)(dst + (size_t)r * HDIM) = acc[r];
}

// K4b: fhid = tanh(sum_ks fpart + b_top); one float4 per thread
extern "C" __global__ __launch_bounds__(256)
void k_ftanh(const float* __restrict__ fpart, const float* __restrict__ btop,
             float* __restrict__ fhid, int nksf) {
  int g = blockIdx.x * 256 + threadIdx.x;   // 65536 float4s
  float4 s = ((const float4*)fpart)[g];
  for (int k = 1; k < nksf; ++k) {
    float4 p = ((const float4*)fpart)[(size_t)k * 65536 + g];
    s.x += p.x; s.y += p.y; s.z += p.z; s.w += p.w;
  }
  float4 b = ((const float4*)btop)[g & 255];
  float4 o;
  o.x = tanhf(s.x + b.x); o.y = tanhf(s.y + b.y);
  o.z = tanhf(s.z + b.z); o.w = tanhf(s.w + b.w);
  ((float4*)fhid)[g] = o;
}

// K5: K-split GEMM partials: part[ks][128][1024] = u(128x4096) @ W1
// u computed on the fly from fhid segments. grid (16 cb, nks ksplits)
extern "C" __global__ __launch_bounds__(256)
void k_part(const float* __restrict__ fhid, const float* __restrict__ W1,
            float* __restrict__ part, int nch) {
  int cb = blockIdx.x, ksb = blockIdx.y;
  int tid = threadIdx.x;
  int cg = tid & 15, rgr = tid >> 4;
  int c0 = cb * 64 + cg * 4;
  int kbase = ksb * nch * 64;
  __shared__ float ush[128 * 64];   // [row][k] 32 KB
  float4 acc[8];
#pragma unroll
  for (int r = 0; r < 8; ++r) acc[r] = make_float4(0.f, 0.f, 0.f, 0.f);
  const float4* f4 = (const float4*)fhid;
  for (int ch = 0; ch < nch; ++ch) {
    int kg = kbase + ch * 64;
    int seg = kg >> 10;
    int fb4 = (kg & 1023) >> 2;
    __syncthreads();
    for (int idx = tid; idx < 128 * 16; idx += 256) {
      int r = idx >> 4, q = idx & 15;
      float4 u;
      if (seg == 0) {
        u = f4[r * 256 + fb4 + q];
      } else if (seg == 1) {
        u = f4[(128 + r) * 256 + fb4 + q];
      } else {
        float4 f1 = f4[r * 256 + fb4 + q];
        float4 f2 = f4[(128 + r) * 256 + fb4 + q];
        if (seg == 2)
          u = make_float4(fabsf(f1.x - f2.x), fabsf(f1.y - f2.y),
                          fabsf(f1.z - f2.z), fabsf(f1.w - f2.w));
        else
          u = make_float4(f1.x * f2.x, f1.y * f2.y, f1.z * f2.z, f1.w * f2.w);
      }
      ((float4*)ush)[idx] = u;
    }
    __syncthreads();
    const float* Wp = W1 + (size_t)kg * HDIM + c0;
    float4 w[4];
#pragma unroll
    for (int j = 0; j < 4; ++j) w[j] = *(const float4*)(Wp + (size_t)j * HDIM);
#pragma unroll
    for (int kk = 0; kk < 64; kk += 4) {
      float4 wn[4];
      if (kk + 4 < 64) {
#pragma unroll
        for (int j = 0; j < 4; ++j) wn[j] = *(const float4*)(Wp + (size_t)(kk + 4 + j) * HDIM);
      }
#pragma unroll
      for (int r = 0; r < 8; ++r) {
        float4 a = *(const float4*)&ush[(rgr * 8 + r) * 64 + kk];
        fma4(acc[r], a.x, w[0]); fma4(acc[r], a.y, w[1]);
        fma4(acc[r], a.z, w[2]); fma4(acc[r], a.w, w[3]);
      }
#pragma unroll
      for (int j = 0; j < 4; ++j) w[j] = wn[j];
    }
  }
  float* dst = part + ((size_t)ksb * 128 + rgr * 8) * HDIM + c0;
#pragma unroll
  for (int r = 0; r < 8; ++r)
    *(float4*)(dst + (size_t)r * HDIM) = acc[r];
}

// K6: out[b,:] += relu(sum_ks part + b1) @ W2 (+ b2 once); grid (128 b, 4 kq)
extern "C" __global__ __launch_bounds__(256)
void k_clf(const float* __restrict__ part, const float* __restrict__ b1,
           const float* __restrict__ W2, const float* __restrict__ b2,
           float* __restrict__ out, int nks) {
  int b = blockIdx.x, kq = blockIdx.y;
  int tid = threadIdx.x;
  int k = kq * 256 + tid;
  float p = b1[k];
  for (int ks = 0; ks < nks; ++ks)
    p += part[((size_t)ks * 128 + b) * HDIM + k];
  p = fmaxf(p, 0.f);
  float a0 = p * W2[k * 3 + 0];
  float a1 = p * W2[k * 3 + 1];
  float a2 = p * W2[k * 3 + 2];
  __shared__ float red[768];
  red[tid] = a0; red[256 + tid] = a1; red[512 + tid] = a2;
  __syncthreads();
  for (int off = 128; off; off >>= 1) {
    if (tid < off) {
      red[tid] += red[tid + off];
      red[256 + tid] += red[256 + tid + off];
      red[512 + tid] += red[512 + tid + off];
    }
    __syncthreads();
  }
  if (tid == 0) {
    float e0 = red[0], e1 = red[256], e2 = red[512];
    if (kq == 0) { e0 += b2[0]; e1 += b2[1]; e2 += b2[2]; }
    atomicAdd(out + b * 3 + 0, e0);
    atomicAdd(out + b * 3 + 1, e1);
    atomicAdd(out + b * 3 + 2, e2);
  }
}

extern "C" void kernel_launch(void* const* d_in, const int* in_sizes, int n_in,
                              void* d_out, int out_size, void* d_ws, size_t ws_size,
                              hipStream_t stream) {
  const int*   seq1  = (const int*)  d_in[0];
  const int*   seq2  = (const int*)  d_in[1];
  const float* emb   = (const float*)d_in[2];
  const float* W_top = (const float*)d_in[3];
  const float* b_top = (const float*)d_in[4];
  const float* W_act = (const float*)d_in[5];
  const float* b_act = (const float*)d_in[6];
  const float* W1    = (const float*)d_in[7];
  const float* b1    = (const float*)d_in[8];
  const float* W2    = (const float*)d_in[9];
  const float* b2    = (const float*)d_in[10];
  float* out = (float*)d_out;
  float* ws  = (float*)d_ws;

  // Config: generous path (bigger K-split => more blocks) if workspace allows.
  // Deterministic across calls (ws_size fixed), so graph-capture-safe.
  bool big = ws_size >= (size_t)20 * 1024 * 1024;
  int nks  = big ? 32 : 16;   // k_part splits  (part = nks*128*1024 floats)
  int nch  = 64 / nks;        // K-chunks of 64 per k_part block
  int nksf = big ? 16 : 8;    // k_fpart splits (fpart = nksf*256*1024 floats)
  int nchf = 16 / nksf;

  float* Eact  = ws + WS_EACT;
  float* delta = ws + WS_DELTA;
  float* diffb = ws + WS_DIFFB;
  int*   tokf  = (int*)(ws + WS_TOKF);
  float* fhid  = ws + WS_FHID;
  float* bigb  = ws + WS_BIG;   // fpart, then (after k_ftanh) reused as part

  hipLaunchKernelGGL(k_eact,  dim3(VOCAB / 4),       dim3(256), 0, stream, emb, W_act, Eact, out);
  hipLaunchKernelGGL(k_stats, dim3(256),             dim3(256), 0, stream, seq1, seq2, Eact, b_act, delta, diffb, tokf);
  hipLaunchKernelGGL(k_final, dim3(1),               dim3(256), 0, stream, delta, diffb, out);
  hipLaunchKernelGGL(k_fpart, dim3(16, 2, nksf),     dim3(256), 0, stream, emb, W_top, tokf, bigb, nchf);
  hipLaunchKernelGGL(k_ftanh, dim3(256),             dim3(256), 0, stream, bigb, b_top, fhid, nksf);
  hipLaunchKernelGGL(k_part,  dim3(16, nks),         dim3(256), 0, stream, fhid, W1, bigb, nch);
  hipLaunchKernelGGL(k_clf,   dim3(128, 4),          dim3(256), 0, stream, bigb, b1, W2, b2, out, nks);
}

// Round 3
// 271.878 us; speedup vs baseline: 1.3282x; 1.0324x over previous
//
#include <hip/hip_runtime.h>
#include <math.h>

#define LL 256
#define BB 128
#define EDIM 1024
#define HDIM 1024
#define VOCAB 32000

#define NKSF 16   // fhid K-splits (K=64 per block)
#define NKS  32   // part K-splits (K=128 per block, 2 chunks of 64)

// workspace layout (float offsets)
#define WS_EACT   0        // 64000
#define WS_DELTA  64000    // 256
#define WS_DIFFB  64256    // 256
#define WS_TOKF   64512    // 256 ints
#define WS_TS     64768    // 256 ints
#define WS_FHID   65024    // 262144
#define WS_BIG    327168   // fpart (16*256*1024) then reused as part (32*128*1024)

#define APAD 68   // LDS staging row stride (64 + 4 pad: kills 4-way bank conflict)

__device__ __forceinline__ void fma4(float4& a, float s, const float4& w) {
  a.x = fmaf(s, w.x, a.x); a.y = fmaf(s, w.y, a.y);
  a.z = fmaf(s, w.z, a.z); a.w = fmaf(s, w.w, a.w);
}

// K_A: per (s,b): lens/Ts/tokf from seq; block 0 zeroes out[0..383] for clf atomics
extern "C" __global__ __launch_bounds__(256)
void k_prep(const int* __restrict__ seq1, const int* __restrict__ seq2,
            int* __restrict__ tokf, int* __restrict__ Tsv, float* __restrict__ out) {
  int bx = blockIdx.x, tid = threadIdx.x;
  if (bx == 0 && tid < 96) ((float4*)out)[tid] = make_float4(0.f, 0.f, 0.f, 0.f);
  int s = bx >> 7, b = bx & 127;
  const int* seq = s ? seq2 : seq1;
  __shared__ int col[LL];
  __shared__ int red[256];
  int v = seq[tid * BB + b];
  col[tid] = v;
  red[tid] = (v == 0) ? 1 : 0;
  __syncthreads();
  for (int off = 128; off; off >>= 1) {
    if (tid < off) red[tid] += red[tid + off];
    __syncthreads();
  }
  if (tid == 0) {
    int lens = LL - red[0] - 1;
    int Ts = 2 * lens - 1;
    Tsv[bx] = Ts;
    int tt = Ts - 1;
    tokf[bx] = (tt < LL) ? col[tt] : col[tt - LL];
  }
}

// K_B: blocks 0..511 = fhid K-split partials; blocks 512..8511 = E_act stream.
// The eact blocks saturate HBM while the fhid blocks (latency-bound, ~10 MB of
// traffic) run concurrently — combined time ~= max, not sum.
extern "C" __global__ __launch_bounds__(256)
void k_fh_eact(const float* __restrict__ emb, const float* __restrict__ Wtop,
               const float* __restrict__ Wact, const int* __restrict__ tokf,
               float* __restrict__ fpart, float* __restrict__ Eact) {
  __shared__ float ash[128 * APAD];
  __shared__ int stok[128];
  int blk = blockIdx.x, tid = threadIdx.x;
  if (blk >= 512) {
    // ---- E_act: one vocab row per wave ----
    int lane = tid & 63, wave = tid >> 6;
    int v = (blk - 512) * 4 + wave;
    const float4* row = (const float4*)(emb + (size_t)v * EDIM);
    const float4* w4 = (const float4*)Wact;
    float a0 = 0.f, a1 = 0.f;
#pragma unroll
    for (int it = 0; it < 4; ++it) {
      int i = lane + it * 64;
      float4 x = row[i];
      float4 wa = w4[2 * i];
      float4 wb = w4[2 * i + 1];
      a0 = fmaf(x.x, wa.x, a0); a0 = fmaf(x.y, wa.z, a0);
      a0 = fmaf(x.z, wb.x, a0); a0 = fmaf(x.w, wb.z, a0);
      a1 = fmaf(x.x, wa.y, a1); a1 = fmaf(x.y, wa.w, a1);
      a1 = fmaf(x.z, wb.y, a1); a1 = fmaf(x.w, wb.w, a1);
    }
#pragma unroll
    for (int off = 32; off; off >>= 1) {
      a0 += __shfl_down(a0, off, 64);
      a1 += __shfl_down(a1, off, 64);
    }
    if (lane == 0) { Eact[2 * v] = a0; Eact[2 * v + 1] = a1; }
    return;
  }
  // ---- fhid partial: ks = blk>>5, rb = (blk>>4)&1, cb = blk&15 ; K slice = 64 ----
  int ks = blk >> 5, rb = (blk >> 4) & 1, cb = blk & 15;
  int cg = tid & 15, rgr = tid >> 4;
  int c0 = cb * 64 + cg * 4;
  int kg = ks * 64;
  if (tid < 128) stok[tid] = tokf[rb * 128 + tid];
  __syncthreads();
  for (int idx = tid; idx < 128 * 16; idx += 256) {
    int r = idx >> 4, q = idx & 15;
    *(float4*)&ash[r * APAD + q * 4] =
        ((const float4*)(emb + (size_t)stok[r] * EDIM + kg))[q];
  }
  __syncthreads();
  const float* Wp = Wtop + (size_t)kg * HDIM + c0;
  float4 acc[8];
#pragma unroll
  for (int r = 0; r < 8; ++r) acc[r] = make_float4(0.f, 0.f, 0.f, 0.f);
  float4 w[4];
#pragma unroll
  for (int j = 0; j < 4; ++j) w[j] = *(const float4*)(Wp + (size_t)j * HDIM);
#pragma unroll
  for (int kk = 0; kk < 64; kk += 4) {
    float4 wn[4];
    if (kk + 4 < 64) {
#pragma unroll
      for (int j = 0; j < 4; ++j) wn[j] = *(const float4*)(Wp + (size_t)(kk + 4 + j) * HDIM);
    }
#pragma unroll
    for (int r = 0; r < 8; ++r) {
      float4 a = *(const float4*)&ash[(rgr * 8 + r) * APAD + kk];
      fma4(acc[r], a.x, w[0]); fma4(acc[r], a.y, w[1]);
      fma4(acc[r], a.z, w[2]); fma4(acc[r], a.w, w[3]);
    }
#pragma unroll
    for (int j = 0; j < 4; ++j) w[j] = wn[j];
  }
  float* dst = fpart + ((size_t)ks * 256 + rb * 128 + rgr * 8) * HDIM + c0;
#pragma unroll
  for (int r = 0; r < 8; ++r)
    *(float4*)(dst + (size_t)r * HDIM) = acc[r];
}

// K_C: fhid = tanh(sum_ks fpart + b_top)
extern "C" __global__ __launch_bounds__(256)
void k_ftanh(const float* __restrict__ fpart, const float* __restrict__ btop,
             float* __restrict__ fhid) {
  int g = blockIdx.x * 256 + threadIdx.x;   // 65536 float4s
  float4 s = ((const float4*)fpart)[g];
#pragma unroll
  for (int k = 1; k < NKSF; ++k) {
    float4 p = ((const float4*)fpart)[(size_t)k * 65536 + g];
    s.x += p.x; s.y += p.y; s.z += p.z; s.w += p.w;
  }
  float4 b = ((const float4*)btop)[g & 255];
  ((float4*)fhid)[g] = make_float4(tanhf(s.x + b.x), tanhf(s.y + b.y),
                                   tanhf(s.z + b.z), tanhf(s.w + b.w));
}

// K_D: blocks 0..511 = u@W1 K-split partials (pipelined staging);
//      blocks 512..767 = ragged softmax stats (needs Eact from K_B).
extern "C" __global__ __launch_bounds__(256)
void k_part_stats(const float* __restrict__ fhid, const float* __restrict__ W1,
                  const int* __restrict__ seq1, const int* __restrict__ seq2,
                  const float* __restrict__ Eact, const float* __restrict__ b_act,
                  const int* __restrict__ Tsv,
                  float* __restrict__ part, float* __restrict__ delta,
                  float* __restrict__ diffb) {
  __shared__ float ush[128 * APAD];
  int blk = blockIdx.x, tid = threadIdx.x;
  if (blk >= 512) {
    // ---- stats for (s,b) ----
    int sb = blk - 512;
    int s = sb >> 7, b = sb & 127;
    const int* seq = s ? seq2 : seq1;
    int* col = (int*)ush;          // ush[0..255]
    float* redf = ush + 256;       // ush[256..511]
    col[tid] = seq[tid * BB + b];
    __syncthreads();
    int Ts = Tsv[sb];
    float ba = b_act[0] - b_act[1];
    float sp = 0.f, sq = 0.f;
    for (int t = tid; t < Ts; t += 256) {
      int tok = (t < LL) ? col[t] : col[t - LL];
      float2 e = ((const float2*)Eact)[tok];
      float d = e.x - e.y + ba;
      float p0 = 1.0f / (1.0f + expf(-d));
      float dd = 2.f * p0 - 1.f;   // push - pop
      sp += dd;
      sq = fmaf(dd, dd, sq);
    }
    redf[tid] = sp; __syncthreads();
    for (int off = 128; off; off >>= 1) { if (tid < off) redf[tid] += redf[tid + off]; __syncthreads(); }
    float tsp = redf[0]; __syncthreads();
    redf[tid] = sq; __syncthreads();
    for (int off = 128; off; off >>= 1) { if (tid < off) redf[tid] += redf[tid + off]; __syncthreads(); }
    if (tid == 0) {
      float Tf = (float)Ts;
      delta[sb] = (tsp - 1.0f) / Tf;
      diffb[sb] = sqrtf(redf[0]) / Tf;
    }
    return;
  }
  // ---- part partial: ksb = blk>>4, cb = blk&15 ; K = 128 in 2 chunks of 64 ----
  int ksb = blk >> 4, cb = blk & 15;
  int cg = tid & 15, rgr = tid >> 4;
  int c0 = cb * 64 + cg * 4;
  int kbase = ksb * 128;
  int seg = kbase >> 10;           // constant across both chunks (128 | 1024)
  const float4* f4 = (const float4*)fhid;
  float4 acc[8];
#pragma unroll
  for (int r = 0; r < 8; ++r) acc[r] = make_float4(0.f, 0.f, 0.f, 0.f);
  float4 sreg[8];
  // gather chunk ch of u into registers (8 float4 per thread)
#define GATHER(ch)                                                        \
  {                                                                       \
    int fb4 = ((kbase + (ch) * 64) & 1023) >> 2;                          \
    _Pragma("unroll")                                                     \
    for (int j = 0; j < 8; ++j) {                                         \
      int idx = tid + j * 256;                                            \
      int r = idx >> 4, q = idx & 15;                                     \
      float4 u;                                                           \
      if (seg == 0) u = f4[r * 256 + fb4 + q];                            \
      else if (seg == 1) u = f4[(128 + r) * 256 + fb4 + q];               \
      else {                                                              \
        float4 f1 = f4[r * 256 + fb4 + q];                                \
        float4 f2 = f4[(128 + r) * 256 + fb4 + q];                        \
        if (seg == 2)                                                     \
          u = make_float4(fabsf(f1.x - f2.x), fabsf(f1.y - f2.y),         \
                          fabsf(f1.z - f2.z), fabsf(f1.w - f2.w));        \
        else                                                              \
          u = make_float4(f1.x * f2.x, f1.y * f2.y, f1.z * f2.z, f1.w * f2.w); \
      }                                                                   \
      sreg[j] = u;                                                        \
    }                                                                     \
  }
  GATHER(0)
#pragma unroll
  for (int ch = 0; ch < 2; ++ch) {
    __syncthreads();
#pragma unroll
    for (int j = 0; j < 8; ++j) {
      int idx = tid + j * 256;
      int r = idx >> 4, q = idx & 15;
      *(float4*)&ush[r * APAD + q * 4] = sreg[j];
    }
    __syncthreads();
    if (ch == 0) GATHER(1)   // global loads overlap chunk-0 FMA below
    int kg = kbase + ch * 64;
    const float* Wp = W1 + (size_t)kg * HDIM + c0;
    float4 w[4];
#pragma unroll
    for (int j = 0; j < 4; ++j) w[j] = *(const float4*)(Wp + (size_t)j * HDIM);
#pragma unroll
    for (int kk = 0; kk < 64; kk += 4) {
      float4 wn[4];
      if (kk + 4 < 64) {
#pragma unroll
        for (int j = 0; j < 4; ++j) wn[j] = *(const float4*)(Wp + (size_t)(kk + 4 + j) * HDIM);
      }
#pragma unroll
      for (int r = 0; r < 8; ++r) {
        float4 a = *(const float4*)&ush[(rgr * 8 + r) * APAD + kk];
        fma4(acc[r], a.x, w[0]); fma4(acc[r], a.y, w[1]);
        fma4(acc[r], a.z, w[2]); fma4(acc[r], a.w, w[3]);
      }
#pragma unroll
      for (int j = 0; j < 4; ++j) w[j] = wn[j];
    }
  }
#undef GATHER
  float* dst = part + ((size_t)ksb * 128 + rgr * 8) * HDIM + c0;
#pragma unroll
  for (int r = 0; r < 8; ++r)
    *(float4*)(dst + (size_t)r * HDIM) = acc[r];
}

// K_E: blocks 0..511 = classifier reduce (b = blk>>2, kq = blk&3); block 512 = dis/diff.
extern "C" __global__ __launch_bounds__(256)
void k_clf_final(const float* __restrict__ part, const float* __restrict__ b1,
                 const float* __restrict__ W2, const float* __restrict__ b2,
                 const float* __restrict__ delta, const float* __restrict__ diffb,
                 float* __restrict__ out) {
  int blk = blockIdx.x, tid = threadIdx.x;
  __shared__ float red[768];
  if (blk == 512) {
    for (int s = 0; s < 2; ++s) {
      float v = 0.f, w = 0.f;
      if (tid < BB) { float d = delta[s * BB + tid]; v = d * d; w = diffb[s * BB + tid]; }
      red[tid] = v; __syncthreads();
      for (int off = 128; off; off >>= 1) { if (tid < off) red[tid] += red[tid + off]; __syncthreads(); }
      if (tid == 0) out[384 + s] = sqrtf(red[0]) / (float)BB;
      __syncthreads();
      red[tid] = w; __syncthreads();
      for (int off = 128; off; off >>= 1) { if (tid < off) red[tid] += red[tid + off]; __syncthreads(); }
      if (tid == 0) out[386 + s] = red[0] / (float)BB;
      __syncthreads();
    }
    return;
  }
  int b = blk >> 2, kq = blk & 3;
  int k = kq * 256 + tid;
  float p = b1[k];
#pragma unroll
  for (int ks = 0; ks < NKS; ++ks)
    p += part[((size_t)ks * 128 + b) * HDIM + k];
  p = fmaxf(p, 0.f);
  float a0 = p * W2[k * 3 + 0];
  float a1 = p * W2[k * 3 + 1];
  float a2 = p * W2[k * 3 + 2];
  red[tid] = a0; red[256 + tid] = a1; red[512 + tid] = a2;
  __syncthreads();
  for (int off = 128; off; off >>= 1) {
    if (tid < off) {
      red[tid] += red[tid + off];
      red[256 + tid] += red[256 + tid + off];
      red[512 + tid] += red[512 + tid + off];
    }
    __syncthreads();
  }
  if (tid == 0) {
    float e0 = red[0], e1 = red[256], e2 = red[512];
    if (kq == 0) { e0 += b2[0]; e1 += b2[1]; e2 += b2[2]; }
    atomicAdd(out + b * 3 + 0, e0);
    atomicAdd(out + b * 3 + 1, e1);
    atomicAdd(out + b * 3 + 2, e2);
  }
}

extern "C" void kernel_launch(void* const* d_in, const int* in_sizes, int n_in,
                              void* d_out, int out_size, void* d_ws, size_t ws_size,
                              hipStream_t stream) {
  const int*   seq1  = (const int*)  d_in[0];
  const int*   seq2  = (const int*)  d_in[1];
  const float* emb   = (const float*)d_in[2];
  const float* W_top = (const float*)d_in[3];
  const float* b_top = (const float*)d_in[4];
  const float* W_act = (const float*)d_in[5];
  const float* b_act = (const float*)d_in[6];
  const float* W1    = (const float*)d_in[7];
  const float* b1    = (const float*)d_in[8];
  const float* W2    = (const float*)d_in[9];
  const float* b2    = (const float*)d_in[10];
  float* out = (float*)d_out;
  float* ws  = (float*)d_ws;

  float* Eact  = ws + WS_EACT;
  float* delta = ws + WS_DELTA;
  float* diffb = ws + WS_DIFFB;
  int*   tokf  = (int*)(ws + WS_TOKF);
  int*   Tsv   = (int*)(ws + WS_TS);
  float* fhid  = ws + WS_FHID;
  float* bigb  = ws + WS_BIG;   // fpart, then reused as part

  hipLaunchKernelGGL(k_prep,       dim3(256),        dim3(256), 0, stream, seq1, seq2, tokf, Tsv, out);
  hipLaunchKernelGGL(k_fh_eact,    dim3(512 + 8000), dim3(256), 0, stream, emb, W_top, W_act, tokf, bigb, Eact);
  hipLaunchKernelGGL(k_ftanh,      dim3(256),        dim3(256), 0, stream, bigb, b_top, fhid);
  hipLaunchKernelGGL(k_part_stats, dim3(768),        dim3(256), 0, stream, fhid, W1, seq1, seq2, Eact, b_act, Tsv, bigb, delta, diffb);
  hipLaunchKernelGGL(k_clf_final,  dim3(513),        dim3(256), 0, stream, bigb, b1, W2, b2, delta, diffb, out);
}

// Round 4
// 265.770 us; speedup vs baseline: 1.3587x; 1.0230x over previous
//
#include <hip/hip_runtime.h>
#include <math.h>

#define LL 256
#define BB 128
#define EDIM 1024
#define HDIM 1024
#define VOCAB 32000

#define NKSF 8    // fhid K-splits (K=128 per block, 2 chunks of 64)
#define NKS  32   // part K-splits (K=128 per block, 2 chunks of 64)

// workspace layout (float offsets)
#define WS_EACT   0        // 32000 (single channel: emb . (w0-w1))
#define WS_DELTA  32000    // 256
#define WS_DIFFB  32256    // 256
#define WS_TOKF   32512    // 256 ints
#define WS_TS     32768    // 256 ints
#define WS_FHID   33024    // 262144
#define WS_BIG    295168   // fpart (8*256*1024=2.1M) then reused as part (32*128*1024=4.2M)

#define APAD 68   // LDS staging row stride (64 + 4 pad: kills 4-way bank conflict)

__device__ __forceinline__ void fma4(float4& a, float s, const float4& w) {
  a.x = fmaf(s, w.x, a.x); a.y = fmaf(s, w.y, a.y);
  a.z = fmaf(s, w.z, a.z); a.w = fmaf(s, w.w, a.w);
}

// K_A: per (s,b): Ts + final token
extern "C" __global__ __launch_bounds__(256)
void k_prep(const int* __restrict__ seq1, const int* __restrict__ seq2,
            int* __restrict__ tokf, int* __restrict__ Tsv) {
  int bx = blockIdx.x, tid = threadIdx.x;
  int s = bx >> 7, b = bx & 127;
  const int* seq = s ? seq2 : seq1;
  __shared__ int col[LL];
  __shared__ int red[256];
  int v = seq[tid * BB + b];
  col[tid] = v;
  red[tid] = (v == 0) ? 1 : 0;
  __syncthreads();
  for (int off = 128; off; off >>= 1) {
    if (tid < off) red[tid] += red[tid + off];
    __syncthreads();
  }
  if (tid == 0) {
    int lens = LL - red[0] - 1;
    int Ts = 2 * lens - 1;
    Tsv[bx] = Ts;
    int tt = Ts - 1;
    tokf[bx] = (tt < LL) ? col[tt] : col[tt - LL];
  }
}

// K_B: blocks 0..255 = fhid K-split partials (K=128, 2 chunks); 256..8255 = E_act stream.
// Latency-bound fhid blocks overlap the BW-bound eact stream on the same CUs.
extern "C" __global__ __launch_bounds__(256)
void k_fh_eact(const float* __restrict__ emb, const float* __restrict__ Wtop,
               const float* __restrict__ Wact, const int* __restrict__ tokf,
               float* __restrict__ fpart, float* __restrict__ Eact) {
  __shared__ float ash[128 * APAD];
  __shared__ int stok[128];
  int blk = blockIdx.x, tid = threadIdx.x;
  if (blk >= 256) {
    // ---- E_act: one vocab row per wave, single channel w0-w1 ----
    int lane = tid & 63, wave = tid >> 6;
    int v = (blk - 256) * 4 + wave;
    const float4* row = (const float4*)(emb + (size_t)v * EDIM);
    const float4* w4 = (const float4*)Wact;   // [e][2] interleaved
    float a0 = 0.f;
#pragma unroll
    for (int it = 0; it < 4; ++it) {
      int i = lane + it * 64;
      float4 x = row[i];
      float4 wa = w4[2 * i];       // {w0[4i],w1[4i],w0[4i+1],w1[4i+1]}
      float4 wb = w4[2 * i + 1];
      a0 = fmaf(x.x, wa.x - wa.y, a0);
      a0 = fmaf(x.y, wa.z - wa.w, a0);
      a0 = fmaf(x.z, wb.x - wb.y, a0);
      a0 = fmaf(x.w, wb.z - wb.w, a0);
    }
#pragma unroll
    for (int off = 32; off; off >>= 1)
      a0 += __shfl_down(a0, off, 64);
    if (lane == 0) Eact[v] = a0;
    return;
  }
  // ---- fhid partial: ks = blk>>5 (8), rb = (blk>>4)&1, cb = blk&15 ; K=128, 2 chunks ----
  int ks = blk >> 5, rb = (blk >> 4) & 1, cb = blk & 15;
  int cg = tid & 15, rgr = tid >> 4;
  int c0 = cb * 64 + cg * 4;
  int kbase = ks * 128;
  if (tid < 128) stok[tid] = tokf[rb * 128 + tid];
  float4 acc[8];
#pragma unroll
  for (int r = 0; r < 8; ++r) acc[r] = make_float4(0.f, 0.f, 0.f, 0.f);
#pragma unroll
  for (int ch = 0; ch < 2; ++ch) {
    int kg = kbase + ch * 64;
    __syncthreads();
    for (int idx = tid; idx < 128 * 16; idx += 256) {
      int r = idx >> 4, q = idx & 15;
      *(float4*)&ash[r * APAD + q * 4] =
          ((const float4*)(emb + (size_t)stok[r] * EDIM + kg))[q];
    }
    __syncthreads();
    const float* Wp = Wtop + (size_t)kg * HDIM + c0;
    float4 w[4];
#pragma unroll
    for (int j = 0; j < 4; ++j) w[j] = *(const float4*)(Wp + (size_t)j * HDIM);
#pragma unroll
    for (int kk = 0; kk < 64; kk += 4) {
      float4 wn[4];
      if (kk + 4 < 64) {
#pragma unroll
        for (int j = 0; j < 4; ++j) wn[j] = *(const float4*)(Wp + (size_t)(kk + 4 + j) * HDIM);
      }
#pragma unroll
      for (int r = 0; r < 8; ++r) {
        float4 a = *(const float4*)&ash[(rgr * 8 + r) * APAD + kk];
        fma4(acc[r], a.x, w[0]); fma4(acc[r], a.y, w[1]);
        fma4(acc[r], a.z, w[2]); fma4(acc[r], a.w, w[3]);
      }
#pragma unroll
      for (int j = 0; j < 4; ++j) w[j] = wn[j];
    }
  }
  float* dst = fpart + ((size_t)ks * 256 + rb * 128 + rgr * 8) * HDIM + c0;
#pragma unroll
  for (int r = 0; r < 8; ++r)
    *(float4*)(dst + (size_t)r * HDIM) = acc[r];
}

// K_C: fhid = tanh(sum_ks fpart + b_top)
extern "C" __global__ __launch_bounds__(256)
void k_ftanh(const float* __restrict__ fpart, const float* __restrict__ btop,
             float* __restrict__ fhid) {
  int g = blockIdx.x * 256 + threadIdx.x;   // 65536 float4s
  float4 s = ((const float4*)fpart)[g];
#pragma unroll
  for (int k = 1; k < NKSF; ++k) {
    float4 p = ((const float4*)fpart)[(size_t)k * 65536 + g];
    s.x += p.x; s.y += p.y; s.z += p.z; s.w += p.w;
  }
  float4 b = ((const float4*)btop)[g & 255];
  ((float4*)fhid)[g] = make_float4(tanhf(s.x + b.x), tanhf(s.y + b.y),
                                   tanhf(s.z + b.z), tanhf(s.w + b.w));
}

// K_D: blocks 0..511 = u@W1 K-split partials (pipelined staging);
//      blocks 512..767 = ragged softmax stats (needs Eact from K_B).
extern "C" __global__ __launch_bounds__(256)
void k_part_stats(const float* __restrict__ fhid, const float* __restrict__ W1,
                  const int* __restrict__ seq1, const int* __restrict__ seq2,
                  const float* __restrict__ Eact, const float* __restrict__ b_act,
                  const int* __restrict__ Tsv,
                  float* __restrict__ part, float* __restrict__ delta,
                  float* __restrict__ diffb) {
  __shared__ float ush[128 * APAD];
  int blk = blockIdx.x, tid = threadIdx.x;
  if (blk >= 512) {
    // ---- stats for (s,b) ----
    int sb = blk - 512;
    int s = sb >> 7, b = sb & 127;
    const int* seq = s ? seq2 : seq1;
    int* col = (int*)ush;
    float* redf = ush + 256;
    col[tid] = seq[tid * BB + b];
    __syncthreads();
    int Ts = Tsv[sb];
    float ba = b_act[0] - b_act[1];
    float sp = 0.f, sq = 0.f;
    for (int t = tid; t < Ts; t += 256) {
      int tok = (t < LL) ? col[t] : col[t - LL];
      float d = Eact[tok] + ba;
      float p0 = 1.0f / (1.0f + expf(-d));
      float dd = 2.f * p0 - 1.f;   // push - pop
      sp += dd;
      sq = fmaf(dd, dd, sq);
    }
    redf[tid] = sp; __syncthreads();
    for (int off = 128; off; off >>= 1) { if (tid < off) redf[tid] += redf[tid + off]; __syncthreads(); }
    float tsp = redf[0]; __syncthreads();
    redf[tid] = sq; __syncthreads();
    for (int off = 128; off; off >>= 1) { if (tid < off) redf[tid] += redf[tid + off]; __syncthreads(); }
    if (tid == 0) {
      float Tf = (float)Ts;
      delta[sb] = (tsp - 1.0f) / Tf;
      diffb[sb] = sqrtf(redf[0]) / Tf;
    }
    return;
  }
  // ---- part partial: ksb = blk>>4, cb = blk&15 ; K = 128 in 2 chunks of 64 ----
  int ksb = blk >> 4, cb = blk & 15;
  int cg = tid & 15, rgr = tid >> 4;
  int c0 = cb * 64 + cg * 4;
  int kbase = ksb * 128;
  int seg = kbase >> 10;
  const float4* f4 = (const float4*)fhid;
  float4 acc[8];
#pragma unroll
  for (int r = 0; r < 8; ++r) acc[r] = make_float4(0.f, 0.f, 0.f, 0.f);
  float4 sreg[8];
#define GATHER(ch)                                                        \
  {                                                                       \
    int fb4 = ((kbase + (ch) * 64) & 1023) >> 2;                          \
    _Pragma("unroll")                                                     \
    for (int j = 0; j < 8; ++j) {                                         \
      int idx = tid + j * 256;                                            \
      int r = idx >> 4, q = idx & 15;                                     \
      float4 u;                                                           \
      if (seg == 0) u = f4[r * 256 + fb4 + q];                            \
      else if (seg == 1) u = f4[(128 + r) * 256 + fb4 + q];               \
      else {                                                              \
        float4 f1 = f4[r * 256 + fb4 + q];                                \
        float4 f2 = f4[(128 + r) * 256 + fb4 + q];                        \
        if (seg == 2)                                                     \
          u = make_float4(fabsf(f1.x - f2.x), fabsf(f1.y - f2.y),         \
                          fabsf(f1.z - f2.z), fabsf(f1.w - f2.w));        \
        else                                                              \
          u = make_float4(f1.x * f2.x, f1.y * f2.y, f1.z * f2.z, f1.w * f2.w); \
      }                                                                   \
      sreg[j] = u;                                                        \
    }                                                                     \
  }
  GATHER(0)
#pragma unroll
  for (int ch = 0; ch < 2; ++ch) {
    __syncthreads();
#pragma unroll
    for (int j = 0; j < 8; ++j) {
      int idx = tid + j * 256;
      int r = idx >> 4, q = idx & 15;
      *(float4*)&ush[r * APAD + q * 4] = sreg[j];
    }
    __syncthreads();
    if (ch == 0) GATHER(1)   // global loads overlap chunk-0 FMA below
    int kg = kbase + ch * 64;
    const float* Wp = W1 + (size_t)kg * HDIM + c0;
    float4 w[4];
#pragma unroll
    for (int j = 0; j < 4; ++j) w[j] = *(const float4*)(Wp + (size_t)j * HDIM);
#pragma unroll
    for (int kk = 0; kk < 64; kk += 4) {
      float4 wn[4];
      if (kk + 4 < 64) {
#pragma unroll
        for (int j = 0; j < 4; ++j) wn[j] = *(const float4*)(Wp + (size_t)(kk + 4 + j) * HDIM);
      }
#pragma unroll
      for (int r = 0; r < 8; ++r) {
        float4 a = *(const float4*)&ush[(rgr * 8 + r) * APAD + kk];
        fma4(acc[r], a.x, w[0]); fma4(acc[r], a.y, w[1]);
        fma4(acc[r], a.z, w[2]); fma4(acc[r], a.w, w[3]);
      }
#pragma unroll
      for (int j = 0; j < 4; ++j) w[j] = wn[j];
    }
  }
#undef GATHER
  float* dst = part + ((size_t)ksb * 128 + rgr * 8) * HDIM + c0;
#pragma unroll
  for (int r = 0; r < 8; ++r)
    *(float4*)(dst + (size_t)r * HDIM) = acc[r];
}

// K_E: blocks 0..127 = classifier for batch b (float4 reduce, direct store);
//      block 128 = dis/diff finals.
extern "C" __global__ __launch_bounds__(256)
void k_clf_final(const float* __restrict__ part, const float* __restrict__ b1,
                 const float* __restrict__ W2, const float* __restrict__ b2,
                 const float* __restrict__ delta, const float* __restrict__ diffb,
                 float* __restrict__ out) {
  int blk = blockIdx.x, tid = threadIdx.x;
  __shared__ float red[768];
  if (blk == 128) {
    for (int s = 0; s < 2; ++s) {
      float v = 0.f, w = 0.f;
      if (tid < BB) { float d = delta[s * BB + tid]; v = d * d; w = diffb[s * BB + tid]; }
      red[tid] = v; __syncthreads();
      for (int off = 128; off; off >>= 1) { if (tid < off) red[tid] += red[tid + off]; __syncthreads(); }
      if (tid == 0) out[384 + s] = sqrtf(red[0]) / (float)BB;
      __syncthreads();
      red[tid] = w; __syncthreads();
      for (int off = 128; off; off >>= 1) { if (tid < off) red[tid] += red[tid + off]; __syncthreads(); }
      if (tid == 0) out[386 + s] = red[0] / (float)BB;
      __syncthreads();
    }
    return;
  }
  int b = blk;
  // thread tid owns float4 k-slice [4*tid, 4*tid+3] of the 1024 hidden units
  float4 p = ((const float4*)b1)[tid];
  const float4* p4 = (const float4*)part;
#pragma unroll
  for (int ks = 0; ks < NKS; ++ks) {
    float4 q = p4[((size_t)ks * 128 + b) * 256 + tid];
    p.x += q.x; p.y += q.y; p.z += q.z; p.w += q.w;
  }
  p.x = fmaxf(p.x, 0.f); p.y = fmaxf(p.y, 0.f);
  p.z = fmaxf(p.z, 0.f); p.w = fmaxf(p.w, 0.f);
  int k0 = tid * 4;
  float a0 = 0.f, a1 = 0.f, a2 = 0.f;
  a0 = fmaf(p.x, W2[(k0 + 0) * 3 + 0], a0); a1 = fmaf(p.x, W2[(k0 + 0) * 3 + 1], a1); a2 = fmaf(p.x, W2[(k0 + 0) * 3 + 2], a2);
  a0 = fmaf(p.y, W2[(k0 + 1) * 3 + 0], a0); a1 = fmaf(p.y, W2[(k0 + 1) * 3 + 1], a1); a2 = fmaf(p.y, W2[(k0 + 1) * 3 + 2], a2);
  a0 = fmaf(p.z, W2[(k0 + 2) * 3 + 0], a0); a1 = fmaf(p.z, W2[(k0 + 2) * 3 + 1], a1); a2 = fmaf(p.z, W2[(k0 + 2) * 3 + 2], a2);
  a0 = fmaf(p.w, W2[(k0 + 3) * 3 + 0], a0); a1 = fmaf(p.w, W2[(k0 + 3) * 3 + 1], a1); a2 = fmaf(p.w, W2[(k0 + 3) * 3 + 2], a2);
  red[tid] = a0; red[256 + tid] = a1; red[512 + tid] = a2;
  __syncthreads();
  for (int off = 128; off; off >>= 1) {
    if (tid < off) {
      red[tid] += red[tid + off];
      red[256 + tid] += red[256 + tid + off];
      red[512 + tid] += red[512 + tid + off];
    }
    __syncthreads();
  }
  if (tid == 0) {
    out[b * 3 + 0] = red[0]   + b2[0];
    out[b * 3 + 1] = red[256] + b2[1];
    out[b * 3 + 2] = red[512] + b2[2];
  }
}

extern "C" void kernel_launch(void* const* d_in, const int* in_sizes, int n_in,
                              void* d_out, int out_size, void* d_ws, size_t ws_size,
                              hipStream_t stream) {
  const int*   seq1  = (const int*)  d_in[0];
  const int*   seq2  = (const int*)  d_in[1];
  const float* emb   = (const float*)d_in[2];
  const float* W_top = (const float*)d_in[3];
  const float* b_top = (const float*)d_in[4];
  const float* W_act = (const float*)d_in[5];
  const float* b_act = (const float*)d_in[6];
  const float* W1    = (const float*)d_in[7];
  const float* b1    = (const float*)d_in[8];
  const float* W2    = (const float*)d_in[9];
  const float* b2    = (const float*)d_in[10];
  float* out = (float*)d_out;
  float* ws  = (float*)d_ws;

  float* Eact  = ws + WS_EACT;
  float* delta = ws + WS_DELTA;
  float* diffb = ws + WS_DIFFB;
  int*   tokf  = (int*)(ws + WS_TOKF);
  int*   Tsv   = (int*)(ws + WS_TS);
  float* fhid  = ws + WS_FHID;
  float* bigb  = ws + WS_BIG;   // fpart, then reused as part

  hipLaunchKernelGGL(k_prep,       dim3(256),        dim3(256), 0, stream, seq1, seq2, tokf, Tsv);
  hipLaunchKernelGGL(k_fh_eact,    dim3(256 + 8000), dim3(256), 0, stream, emb, W_top, W_act, tokf, bigb, Eact);
  hipLaunchKernelGGL(k_ftanh,      dim3(256),        dim3(256), 0, stream, bigb, b_top, fhid);
  hipLaunchKernelGGL(k_part_stats, dim3(768),        dim3(256), 0, stream, fhid, W1, seq1, seq2, Eact, b_act, Tsv, bigb, delta, diffb);
  hipLaunchKernelGGL(k_clf_final,  dim3(129),        dim3(256), 0, stream, bigb, b1, W2, b2, delta, diffb, out);
}

// Round 5
// 258.696 us; speedup vs baseline: 1.3959x; 1.0273x over previous
//
#include <hip/hip_runtime.h>
#include <math.h>

#define LL 256
#define BB 128
#define EDIM 1024
#define HDIM 1024
#define VOCAB 32000

#define NKSF 8    // fhid K-splits (K=128 per block, 2 chunks of 64)
#define NKS  64   // part K-splits (K=64 per block, single chunk)

// workspace layout (float offsets)
#define WS_EACT   0        // 32000 (single channel: emb . (w0-w1))
#define WS_DELTA  32000    // 256
#define WS_DIFFB  32256    // 256
#define WS_FHID   33024    // 262144
#define WS_BIG    295168   // fpart (8*256*1024=2.1M) then reused as part (64*128*1024=8.4M)

#define APAD 68   // LDS staging row stride (64 + 4 pad: kills 4-way bank conflict)

__device__ __forceinline__ void fma4(float4& a, float s, const float4& w) {
  a.x = fmaf(s, w.x, a.x); a.y = fmaf(s, w.y, a.y);
  a.z = fmaf(s, w.z, a.z); a.w = fmaf(s, w.w, a.w);
}

// K_B: blocks 0..255 = fhid K-split partials (self-compute final tokens);
//      blocks 256..8255 = E_act stream. Latency-bound fhid blocks hide under
//      the BW-bound eact stream.
extern "C" __global__ __launch_bounds__(256)
void k_fh_eact(const float* __restrict__ emb, const float* __restrict__ Wtop,
               const float* __restrict__ Wact,
               const int* __restrict__ seq1, const int* __restrict__ seq2,
               float* __restrict__ fpart, float* __restrict__ Eact) {
  __shared__ float ash[128 * APAD];
  __shared__ int stok[128];
  int blk = blockIdx.x, tid = threadIdx.x;
  if (blk >= 256) {
    // ---- E_act: one vocab row per wave, single channel (w0 - w1) ----
    int lane = tid & 63, wave = tid >> 6;
    int v = (blk - 256) * 4 + wave;
    const float4* row = (const float4*)(emb + (size_t)v * EDIM);
    const float4* w4 = (const float4*)Wact;   // [e][2] interleaved
    float a0 = 0.f;
#pragma unroll
    for (int it = 0; it < 4; ++it) {
      int i = lane + it * 64;
      float4 x = row[i];
      float4 wa = w4[2 * i];
      float4 wb = w4[2 * i + 1];
      a0 = fmaf(x.x, wa.x - wa.y, a0);
      a0 = fmaf(x.y, wa.z - wa.w, a0);
      a0 = fmaf(x.z, wb.x - wb.y, a0);
      a0 = fmaf(x.w, wb.z - wb.w, a0);
    }
#pragma unroll
    for (int off = 32; off; off >>= 1)
      a0 += __shfl_down(a0, off, 64);
    if (lane == 0) Eact[v] = a0;
    return;
  }
  // ---- fhid partial: ks = blk>>5 (8), rb = (blk>>4)&1, cb = blk&15 ; K=128 ----
  int ks = blk >> 5, rb = (blk >> 4) & 1, cb = blk & 15;
  int cg = tid & 15, rgr = tid >> 4;
  int c0 = cb * 64 + cg * 4;
  int kbase = ks * 128;
  const int* seq = rb ? seq2 : seq1;
  // self-compute final tokens for this rb half: 2 threads per batch column
  {
    int c = tid >> 1, h = tid & 1;
    int z = 0;
    int base = h * 128;
    for (int r = 0; r < 128; ++r)
      z += (seq[(base + r) * BB + c] == 0) ? 1 : 0;
    z += __shfl_xor(z, 1, 64);
    if (h == 0) {
      int lens = 255 - z;           // L - pads - 1
      int tt = 2 * lens - 2;        // Ts - 1
      int idx = (tt < LL) ? tt : tt - LL;
      stok[c] = seq[idx * BB + c];
    }
  }
  float4 acc[8];
#pragma unroll
  for (int r = 0; r < 8; ++r) acc[r] = make_float4(0.f, 0.f, 0.f, 0.f);
#pragma unroll
  for (int ch = 0; ch < 2; ++ch) {
    int kg = kbase + ch * 64;
    __syncthreads();
    for (int idx = tid; idx < 128 * 16; idx += 256) {
      int r = idx >> 4, q = idx & 15;
      *(float4*)&ash[r * APAD + q * 4] =
          ((const float4*)(emb + (size_t)stok[r] * EDIM + kg))[q];
    }
    __syncthreads();
    const float* Wp = Wtop + (size_t)kg * HDIM + c0;
    float4 w[4];
#pragma unroll
    for (int j = 0; j < 4; ++j) w[j] = *(const float4*)(Wp + (size_t)j * HDIM);
#pragma unroll
    for (int kk = 0; kk < 64; kk += 4) {
      float4 wn[4];
      if (kk + 4 < 64) {
#pragma unroll
        for (int j = 0; j < 4; ++j) wn[j] = *(const float4*)(Wp + (size_t)(kk + 4 + j) * HDIM);
      }
#pragma unroll
      for (int r = 0; r < 8; ++r) {
        float4 a = *(const float4*)&ash[(rgr * 8 + r) * APAD + kk];
        fma4(acc[r], a.x, w[0]); fma4(acc[r], a.y, w[1]);
        fma4(acc[r], a.z, w[2]); fma4(acc[r], a.w, w[3]);
      }
#pragma unroll
      for (int j = 0; j < 4; ++j) w[j] = wn[j];
    }
  }
  float* dst = fpart + ((size_t)ks * 256 + rb * 128 + rgr * 8) * HDIM + c0;
#pragma unroll
  for (int r = 0; r < 8; ++r)
    *(float4*)(dst + (size_t)r * HDIM) = acc[r];
}

// K_C: blocks 0..255 = fhid = tanh(sum_ks fpart + b_top);
//      blocks 256..511 = ragged softmax stats (self-compute Ts).
extern "C" __global__ __launch_bounds__(256)
void k_ftanh_stats(const float* __restrict__ fpart, const float* __restrict__ btop,
                   const int* __restrict__ seq1, const int* __restrict__ seq2,
                   const float* __restrict__ Eact, const float* __restrict__ b_act,
                   float* __restrict__ fhid, float* __restrict__ delta,
                   float* __restrict__ diffb) {
  int blk = blockIdx.x, tid = threadIdx.x;
  if (blk < 256) {
    int g = blk * 256 + tid;   // 65536 float4s
    float4 s = ((const float4*)fpart)[g];
#pragma unroll
    for (int k = 1; k < NKSF; ++k) {
      float4 p = ((const float4*)fpart)[(size_t)k * 65536 + g];
      s.x += p.x; s.y += p.y; s.z += p.z; s.w += p.w;
    }
    float4 b = ((const float4*)btop)[g & 255];
    ((float4*)fhid)[g] = make_float4(tanhf(s.x + b.x), tanhf(s.y + b.y),
                                     tanhf(s.z + b.z), tanhf(s.w + b.w));
    return;
  }
  // ---- stats for (s,b) ----
  int sb = blk - 256;
  int s = sb >> 7, b = sb & 127;
  const int* seq = s ? seq2 : seq1;
  __shared__ int col[LL];
  __shared__ int zred[256];
  __shared__ float redf[256];
  int v = seq[tid * BB + b];
  col[tid] = v;
  zred[tid] = (v == 0) ? 1 : 0;
  __syncthreads();
  for (int off = 128; off; off >>= 1) {
    if (tid < off) zred[tid] += zred[tid + off];
    __syncthreads();
  }
  int lens = LL - zred[0] - 1;
  int Ts = 2 * lens - 1;
  float ba = b_act[0] - b_act[1];
  float sp = 0.f, sq = 0.f;
  for (int t = tid; t < Ts; t += 256) {
    int tok = (t < LL) ? col[t] : col[t - LL];
    float d = Eact[tok] + ba;
    float p0 = 1.0f / (1.0f + expf(-d));
    float dd = 2.f * p0 - 1.f;   // push - pop
    sp += dd;
    sq = fmaf(dd, dd, sq);
  }
  redf[tid] = sp; __syncthreads();
  for (int off = 128; off; off >>= 1) { if (tid < off) redf[tid] += redf[tid + off]; __syncthreads(); }
  float tsp = redf[0]; __syncthreads();
  redf[tid] = sq; __syncthreads();
  for (int off = 128; off; off >>= 1) { if (tid < off) redf[tid] += redf[tid + off]; __syncthreads(); }
  if (tid == 0) {
    float Tf = (float)Ts;
    delta[sb] = (tsp - 1.0f) / Tf;
    diffb[sb] = sqrtf(redf[0]) / Tf;
  }
}

// K_D: u@W1 K-split partials; 1024 blocks (ksb = blk>>4, cb = blk&15), K=64 each.
extern "C" __global__ __launch_bounds__(256)
void k_part(const float* __restrict__ fhid, const float* __restrict__ W1,
            float* __restrict__ part) {
  __shared__ float ush[128 * APAD];
  int blk = blockIdx.x, tid = threadIdx.x;
  int ksb = blk >> 4, cb = blk & 15;
  int cg = tid & 15, rgr = tid >> 4;
  int c0 = cb * 64 + cg * 4;
  int kbase = ksb * 64;
  int seg = kbase >> 10;
  int fb4 = (kbase & 1023) >> 2;
  const float4* f4 = (const float4*)fhid;
  // gather u chunk into LDS (through regs)
#pragma unroll
  for (int j = 0; j < 8; ++j) {
    int idx = tid + j * 256;
    int r = idx >> 4, q = idx & 15;
    float4 u;
    if (seg == 0) u = f4[r * 256 + fb4 + q];
    else if (seg == 1) u = f4[(128 + r) * 256 + fb4 + q];
    else {
      float4 f1 = f4[r * 256 + fb4 + q];
      float4 f2 = f4[(128 + r) * 256 + fb4 + q];
      if (seg == 2)
        u = make_float4(fabsf(f1.x - f2.x), fabsf(f1.y - f2.y),
                        fabsf(f1.z - f2.z), fabsf(f1.w - f2.w));
      else
        u = make_float4(f1.x * f2.x, f1.y * f2.y, f1.z * f2.z, f1.w * f2.w);
    }
    *(float4*)&ush[r * APAD + q * 4] = u;
  }
  float4 acc[8];
#pragma unroll
  for (int r = 0; r < 8; ++r) acc[r] = make_float4(0.f, 0.f, 0.f, 0.f);
  __syncthreads();
  const float* Wp = W1 + (size_t)kbase * HDIM + c0;
  float4 w[4];
#pragma unroll
  for (int j = 0; j < 4; ++j) w[j] = *(const float4*)(Wp + (size_t)j * HDIM);
#pragma unroll
  for (int kk = 0; kk < 64; kk += 4) {
    float4 wn[4];
    if (kk + 4 < 64) {
#pragma unroll
      for (int j = 0; j < 4; ++j) wn[j] = *(const float4*)(Wp + (size_t)(kk + 4 + j) * HDIM);
    }
#pragma unroll
    for (int r = 0; r < 8; ++r) {
      float4 a = *(const float4*)&ush[(rgr * 8 + r) * APAD + kk];
      fma4(acc[r], a.x, w[0]); fma4(acc[r], a.y, w[1]);
      fma4(acc[r], a.z, w[2]); fma4(acc[r], a.w, w[3]);
    }
#pragma unroll
    for (int j = 0; j < 4; ++j) w[j] = wn[j];
  }
  float* dst = part + ((size_t)ksb * 128 + rgr * 8) * HDIM + c0;
#pragma unroll
  for (int r = 0; r < 8; ++r)
    *(float4*)(dst + (size_t)r * HDIM) = acc[r];
}

// K_E: blocks 0..127 = classifier for batch b (float4 reduce, direct store);
//      block 128 = dis/diff finals.
extern "C" __global__ __launch_bounds__(256)
void k_clf_final(const float* __restrict__ part, const float* __restrict__ b1,
                 const float* __restrict__ W2, const float* __restrict__ b2,
                 const float* __restrict__ delta, const float* __restrict__ diffb,
                 float* __restrict__ out) {
  int blk = blockIdx.x, tid = threadIdx.x;
  __shared__ float red[768];
  if (blk == 128) {
    for (int s = 0; s < 2; ++s) {
      float v = 0.f, w = 0.f;
      if (tid < BB) { float d = delta[s * BB + tid]; v = d * d; w = diffb[s * BB + tid]; }
      red[tid] = v; __syncthreads();
      for (int off = 128; off; off >>= 1) { if (tid < off) red[tid] += red[tid + off]; __syncthreads(); }
      if (tid == 0) out[384 + s] = sqrtf(red[0]) / (float)BB;
      __syncthreads();
      red[tid] = w; __syncthreads();
      for (int off = 128; off; off >>= 1) { if (tid < off) red[tid] += red[tid + off]; __syncthreads(); }
      if (tid == 0) out[386 + s] = red[0] / (float)BB;
      __syncthreads();
    }
    return;
  }
  int b = blk;
  float4 p = ((const float4*)b1)[tid];
  const float4* p4 = (const float4*)part;
  for (int ks = 0; ks < NKS; ++ks) {
    float4 q = p4[((size_t)ks * 128 + b) * 256 + tid];
    p.x += q.x; p.y += q.y; p.z += q.z; p.w += q.w;
  }
  p.x = fmaxf(p.x, 0.f); p.y = fmaxf(p.y, 0.f);
  p.z = fmaxf(p.z, 0.f); p.w = fmaxf(p.w, 0.f);
  int k0 = tid * 4;
  float a0 = 0.f, a1 = 0.f, a2 = 0.f;
  a0 = fmaf(p.x, W2[(k0 + 0) * 3 + 0], a0); a1 = fmaf(p.x, W2[(k0 + 0) * 3 + 1], a1); a2 = fmaf(p.x, W2[(k0 + 0) * 3 + 2], a2);
  a0 = fmaf(p.y, W2[(k0 + 1) * 3 + 0], a0); a1 = fmaf(p.y, W2[(k0 + 1) * 3 + 1], a1); a2 = fmaf(p.y, W2[(k0 + 1) * 3 + 2], a2);
  a0 = fmaf(p.z, W2[(k0 + 2) * 3 + 0], a0); a1 = fmaf(p.z, W2[(k0 + 2) * 3 + 1], a1); a2 = fmaf(p.z, W2[(k0 + 2) * 3 + 2], a2);
  a0 = fmaf(p.w, W2[(k0 + 3) * 3 + 0], a0); a1 = fmaf(p.w, W2[(k0 + 3) * 3 + 1], a1); a2 = fmaf(p.w, W2[(k0 + 3) * 3 + 2], a2);
  red[tid] = a0; red[256 + tid] = a1; red[512 + tid] = a2;
  __syncthreads();
  for (int off = 128; off; off >>= 1) {
    if (tid < off) {
      red[tid] += red[tid + off];
      red[256 + tid] += red[256 + tid + off];
      red[512 + tid] += red[512 + tid + off];
    }
    __syncthreads();
  }
  if (tid == 0) {
    out[b * 3 + 0] = red[0]   + b2[0];
    out[b * 3 + 1] = red[256] + b2[1];
    out[b * 3 + 2] = red[512] + b2[2];
  }
}

extern "C" void kernel_launch(void* const* d_in, const int* in_sizes, int n_in,
                              void* d_out, int out_size, void* d_ws, size_t ws_size,
                              hipStream_t stream) {
  const int*   seq1  = (const int*)  d_in[0];
  const int*   seq2  = (const int*)  d_in[1];
  const float* emb   = (const float*)d_in[2];
  const float* W_top = (const float*)d_in[3];
  const float* b_top = (const float*)d_in[4];
  const float* W_act = (const float*)d_in[5];
  const float* b_act = (const float*)d_in[6];
  const float* W1    = (const float*)d_in[7];
  const float* b1    = (const float*)d_in[8];
  const float* W2    = (const float*)d_in[9];
  const float* b2    = (const float*)d_in[10];
  float* out = (float*)d_out;
  float* ws  = (float*)d_ws;

  float* Eact  = ws + WS_EACT;
  float* delta = ws + WS_DELTA;
  float* diffb = ws + WS_DIFFB;
  float* fhid  = ws + WS_FHID;
  float* bigb  = ws + WS_BIG;   // fpart, then reused as part

  hipLaunchKernelGGL(k_fh_eact,     dim3(256 + 8000), dim3(256), 0, stream, emb, W_top, W_act, seq1, seq2, bigb, Eact);
  hipLaunchKernelGGL(k_ftanh_stats, dim3(512),        dim3(256), 0, stream, bigb, b_top, seq1, seq2, Eact, b_act, fhid, delta, diffb);
  hipLaunchKernelGGL(k_part,        dim3(1024),       dim3(256), 0, stream, fhid, W1, bigb);
  hipLaunchKernelGGL(k_clf_final,   dim3(129),        dim3(256), 0, stream, bigb, b1, W2, b2, delta, diffb, out);
}

// Round 7
// 257.955 us; speedup vs baseline: 1.3999x; 1.0029x over previous
//
#include <hip/hip_runtime.h>
#include <math.h>

#define LL 256
#define BB 128
#define EDIM 1024
#define HDIM 1024
#define VOCAB 32000

#define NKSF 8    // fhid K-splits (K=128 per block, 2 chunks of 64)
#define NKS  64   // part K-splits (K=64 per block, single chunk)

// workspace layout (float offsets)
#define WS_EACT   0        // 32000 (single channel: emb . (w0-w1))
#define WS_DELTA  32000    // 256
#define WS_DIFFB  32256    // 256
#define WS_FHID   33024    // 262144
#define WS_BIG    295168   // fpart (8*256*1024=2.1M) then reused as part (64*128*1024=8.4M)

#define APAD 68   // LDS staging row stride (64 + 4 pad: kills 4-way bank conflict)

__device__ __forceinline__ void fma4(float4& a, float s, const float4& w) {
  a.x = fmaf(s, w.x, a.x); a.y = fmaf(s, w.y, a.y);
  a.z = fmaf(s, w.z, a.z); a.w = fmaf(s, w.w, a.w);
}

// K_B: blocks 0..255 = fhid K-split partials (self-compute final tokens);
//      blocks 256..8255 = E_act stream. Latency-bound fhid blocks hide under
//      the BW-bound eact stream.
extern "C" __global__ __launch_bounds__(256)
void k_fh_eact(const float* __restrict__ emb, const float* __restrict__ Wtop,
               const float* __restrict__ Wact,
               const int* __restrict__ seq1, const int* __restrict__ seq2,
               float* __restrict__ fpart, float* __restrict__ Eact) {
  __shared__ float ash[128 * APAD];
  __shared__ int stok[128];
  int blk = blockIdx.x, tid = threadIdx.x;
  if (blk >= 256) {
    // ---- E_act: one vocab row per wave, single channel (w0 - w1) ----
    int lane = tid & 63, wave = tid >> 6;
    int v = (blk - 256) * 4 + wave;
    const float4* row = (const float4*)(emb + (size_t)v * EDIM);
    const float4* w4 = (const float4*)Wact;   // [e][2] interleaved
    float a0 = 0.f;
#pragma unroll
    for (int it = 0; it < 4; ++it) {
      int i = lane + it * 64;
      float4 x = row[i];
      float4 wa = w4[2 * i];
      float4 wb = w4[2 * i + 1];
      a0 = fmaf(x.x, wa.x - wa.y, a0);
      a0 = fmaf(x.y, wa.z - wa.w, a0);
      a0 = fmaf(x.z, wb.x - wb.y, a0);
      a0 = fmaf(x.w, wb.z - wb.w, a0);
    }
#pragma unroll
    for (int off = 32; off; off >>= 1)
      a0 += __shfl_down(a0, off, 64);
    if (lane == 0) Eact[v] = a0;
    return;
  }
  // ---- fhid partial: ks = blk>>5 (8), rb = (blk>>4)&1, cb = blk&15 ; K=128 ----
  int ks = blk >> 5, rb = (blk >> 4) & 1, cb = blk & 15;
  int cg = tid & 15, rgr = tid >> 4;
  int c0 = cb * 64 + cg * 4;
  int kbase = ks * 128;
  const int* seq = rb ? seq2 : seq1;
  // self-compute final tokens for this rb half: 2 threads per batch column
  {
    int c = tid >> 1, h = tid & 1;
    int z = 0;
    int base = h * 128;
    for (int r = 0; r < 128; ++r)
      z += (seq[(base + r) * BB + c] == 0) ? 1 : 0;
    z += __shfl_xor(z, 1, 64);
    if (h == 0) {
      int lens = 255 - z;           // L - pads - 1
      int tt = 2 * lens - 2;        // Ts - 1
      int idx = (tt < LL) ? tt : tt - LL;
      stok[c] = seq[idx * BB + c];
    }
  }
  float4 acc[8];
#pragma unroll
  for (int r = 0; r < 8; ++r) acc[r] = make_float4(0.f, 0.f, 0.f, 0.f);
#pragma unroll
  for (int ch = 0; ch < 2; ++ch) {
    int kg = kbase + ch * 64;
    __syncthreads();
    for (int idx = tid; idx < 128 * 16; idx += 256) {
      int r = idx >> 4, q = idx & 15;
      *(float4*)&ash[r * APAD + q * 4] =
          ((const float4*)(emb + (size_t)stok[r] * EDIM + kg))[q];
    }
    __syncthreads();
    const float* Wp = Wtop + (size_t)kg * HDIM + c0;
    float4 w[4];
#pragma unroll
    for (int j = 0; j < 4; ++j) w[j] = *(const float4*)(Wp + (size_t)j * HDIM);
#pragma unroll
    for (int kk = 0; kk < 64; kk += 4) {
      float4 wn[4];
      if (kk + 4 < 64) {
#pragma unroll
        for (int j = 0; j < 4; ++j) wn[j] = *(const float4*)(Wp + (size_t)(kk + 4 + j) * HDIM);
      }
#pragma unroll
      for (int r = 0; r < 8; ++r) {
        float4 a = *(const float4*)&ash[(rgr * 8 + r) * APAD + kk];
        fma4(acc[r], a.x, w[0]); fma4(acc[r], a.y, w[1]);
        fma4(acc[r], a.z, w[2]); fma4(acc[r], a.w, w[3]);
      }
#pragma unroll
      for (int j = 0; j < 4; ++j) w[j] = wn[j];
    }
  }
  float* dst = fpart + ((size_t)ks * 256 + rb * 128 + rgr * 8) * HDIM + c0;
#pragma unroll
  for (int r = 0; r < 8; ++r)
    *(float4*)(dst + (size_t)r * HDIM) = acc[r];
}

// K_C: blocks 0..255 = fhid = tanh(sum_ks fpart + b_top);
//      blocks 256..511 = ragged softmax stats (self-compute Ts).
extern "C" __global__ __launch_bounds__(256)
void k_ftanh_stats(const float* __restrict__ fpart, const float* __restrict__ btop,
                   const int* __restrict__ seq1, const int* __restrict__ seq2,
                   const float* __restrict__ Eact, const float* __restrict__ b_act,
                   float* __restrict__ fhid, float* __restrict__ delta,
                   float* __restrict__ diffb) {
  int blk = blockIdx.x, tid = threadIdx.x;
  if (blk < 256) {
    int g = blk * 256 + tid;   // 65536 float4s
    float4 s = ((const float4*)fpart)[g];
#pragma unroll
    for (int k = 1; k < NKSF; ++k) {
      float4 p = ((const float4*)fpart)[(size_t)k * 65536 + g];
      s.x += p.x; s.y += p.y; s.z += p.z; s.w += p.w;
    }
    float4 b = ((const float4*)btop)[g & 255];
    ((float4*)fhid)[g] = make_float4(tanhf(s.x + b.x), tanhf(s.y + b.y),
                                     tanhf(s.z + b.z), tanhf(s.w + b.w));
    return;
  }
  // ---- stats for (s,b) ----
  int sb = blk - 256;
  int s = sb >> 7, b = sb & 127;
  const int* seq = s ? seq2 : seq1;
  __shared__ int col[LL];
  __shared__ int zred[256];
  __shared__ float redf[256];
  int v = seq[tid * BB + b];
  col[tid] = v;
  zred[tid] = (v == 0) ? 1 : 0;
  __syncthreads();
  for (int off = 128; off; off >>= 1) {
    if (tid < off) zred[tid] += zred[tid + off];
    __syncthreads();
  }
  int lens = LL - zred[0] - 1;
  int Ts = 2 * lens - 1;
  float ba = b_act[0] - b_act[1];
  float sp = 0.f, sq = 0.f;
  for (int t = tid; t < Ts; t += 256) {
    int tok = (t < LL) ? col[t] : col[t - LL];
    float d = Eact[tok] + ba;
    float p0 = 1.0f / (1.0f + expf(-d));
    float dd = 2.f * p0 - 1.f;   // push - pop
    sp += dd;
    sq = fmaf(dd, dd, sq);
  }
  redf[tid] = sp; __syncthreads();
  for (int off = 128; off; off >>= 1) { if (tid < off) redf[tid] += redf[tid + off]; __syncthreads(); }
  float tsp = redf[0]; __syncthreads();
  redf[tid] = sq; __syncthreads();
  for (int off = 128; off; off >>= 1) { if (tid < off) redf[tid] += redf[tid + off]; __syncthreads(); }
  if (tid == 0) {
    float Tf = (float)Ts;
    delta[sb] = (tsp - 1.0f) / Tf;
    diffb[sb] = sqrtf(redf[0]) / Tf;
  }
}

// K_D: u@W1 K-split partials; 1024 blocks (ksb = blk>>4, cb = blk&15), K=64 each.
extern "C" __global__ __launch_bounds__(256)
void k_part(const float* __restrict__ fhid, const float* __restrict__ W1,
            float* __restrict__ part) {
  __shared__ float ush[128 * APAD];
  int blk = blockIdx.x, tid = threadIdx.x;
  int ksb = blk >> 4, cb = blk & 15;
  int cg = tid & 15, rgr = tid >> 4;
  int c0 = cb * 64 + cg * 4;
  int kbase = ksb * 64;
  int seg = kbase >> 10;
  int fb4 = (kbase & 1023) >> 2;
  const float4* f4 = (const float4*)fhid;
  // gather u chunk into LDS (through regs)
#pragma unroll
  for (int j = 0; j < 8; ++j) {
    int idx = tid + j * 256;
    int r = idx >> 4, q = idx & 15;
    float4 u;
    if (seg == 0) u = f4[r * 256 + fb4 + q];
    else if (seg == 1) u = f4[(128 + r) * 256 + fb4 + q];
    else {
      float4 f1 = f4[r * 256 + fb4 + q];
      float4 f2 = f4[(128 + r) * 256 + fb4 + q];
      if (seg == 2)
        u = make_float4(fabsf(f1.x - f2.x), fabsf(f1.y - f2.y),
                        fabsf(f1.z - f2.z), fabsf(f1.w - f2.w));
      else
        u = make_float4(f1.x * f2.x, f1.y * f2.y, f1.z * f2.z, f1.w * f2.w);
    }
    *(float4*)&ush[r * APAD + q * 4] = u;
  }
  float4 acc[8];
#pragma unroll
  for (int r = 0; r < 8; ++r) acc[r] = make_float4(0.f, 0.f, 0.f, 0.f);
  __syncthreads();
  const float* Wp = W1 + (size_t)kbase * HDIM + c0;
  float4 w[4];
#pragma unroll
  for (int j = 0; j < 4; ++j) w[j] = *(const float4*)(Wp + (size_t)j * HDIM);
#pragma unroll
  for (int kk = 0; kk < 64; kk += 4) {
    float4 wn[4];
    if (kk + 4 < 64) {
#pragma unroll
      for (int j = 0; j < 4; ++j) wn[j] = *(const float4*)(Wp + (size_t)(kk + 4 + j) * HDIM);
    }
#pragma unroll
    for (int r = 0; r < 8; ++r) {
      float4 a = *(const float4*)&ush[(rgr * 8 + r) * APAD + kk];
      fma4(acc[r], a.x, w[0]); fma4(acc[r], a.y, w[1]);
      fma4(acc[r], a.z, w[2]); fma4(acc[r], a.w, w[3]);
    }
#pragma unroll
    for (int j = 0; j < 4; ++j) w[j] = wn[j];
  }
  float* dst = part + ((size_t)ksb * 128 + rgr * 8) * HDIM + c0;
#pragma unroll
  for (int r = 0; r < 8; ++r)
    *(float4*)(dst + (size_t)r * HDIM) = acc[r];
}

// K_E: blocks 0..127 = classifier for batch b (float4 reduce, direct store);
//      block 128 = dis/diff finals.
extern "C" __global__ __launch_bounds__(256)
void k_clf_final(const float* __restrict__ part, const float* __restrict__ b1,
                 const float* __restrict__ W2, const float* __restrict__ b2,
                 const float* __restrict__ delta, const float* __restrict__ diffb,
                 float* __restrict__ out) {
  int blk = blockIdx.x, tid = threadIdx.x;
  __shared__ float red[768];
  if (blk == 128) {
    for (int s = 0; s < 2; ++s) {
      float v = 0.f, w = 0.f;
      if (tid < BB) { float d = delta[s * BB + tid]; v = d * d; w = diffb[s * BB + tid]; }
      red[tid] = v; __syncthreads();
      for (int off = 128; off; off >>= 1) { if (tid < off) red[tid] += red[tid + off]; __syncthreads(); }
      if (tid == 0) out[384 + s] = sqrtf(red[0]) / (float)BB;
      __syncthreads();
      red[tid] = w; __syncthreads();
      for (int off = 128; off; off >>= 1) { if (tid < off) red[tid] += red[tid + off]; __syncthreads(); }
      if (tid == 0) out[386 + s] = red[0] / (float)BB;
      __syncthreads();
    }
    return;
  }
  int b = blk;
  float4 p = ((const float4*)b1)[tid];
  const float4* p4 = (const float4*)part;
  for (int ks = 0; ks < NKS; ++ks) {
    float4 q = p4[((size_t)ks * 128 + b) * 256 + tid];
    p.x += q.x; p.y += q.y; p.z += q.z; p.w += q.w;
  }
  p.x = fmaxf(p.x, 0.f); p.y = fmaxf(p.y, 0.f);
  p.z = fmaxf(p.z, 0.f); p.w = fmaxf(p.w, 0.f);
  int k0 = tid * 4;
  float a0 = 0.f, a1 = 0.f, a2 = 0.f;
  a0 = fmaf(p.x, W2[(k0 + 0) * 3 + 0], a0); a1 = fmaf(p.x, W2[(k0 + 0) * 3 + 1], a1); a2 = fmaf(p.x, W2[(k0 + 0) * 3 + 2], a2);
  a0 = fmaf(p.y, W2[(k0 + 1) * 3 + 0], a0); a1 = fmaf(p.y, W2[(k0 + 1) * 3 + 1], a1); a2 = fmaf(p.y, W2[(k0 + 1) * 3 + 2], a2);
  a0 = fmaf(p.z, W2[(k0 + 2) * 3 + 0], a0); a1 = fmaf(p.z, W2[(k0 + 2) * 3 + 1], a1); a2 = fmaf(p.z, W2[(k0 + 2) * 3 + 2], a2);
  a0 = fmaf(p.w, W2[(k0 + 3) * 3 + 0], a0); a1 = fmaf(p.w, W2[(k0 + 3) * 3 + 1], a1); a2 = fmaf(p.w, W2[(k0 + 3) * 3 + 2], a2);
  red[tid] = a0; red[256 + tid] = a1; red[512 + tid] = a2;
  __syncthreads();
  for (int off = 128; off; off >>= 1) {
    if (tid < off) {
      red[tid] += red[tid + off];
      red[256 + tid] += red[256 + tid + off];
      red[512 + tid] += red[512 + tid + off];
    }
    __syncthreads();
  }
  if (tid == 0) {
    out[b * 3 + 0] = red[0]   + b2[0];
    out[b * 3 + 1] = red[256] + b2[1];
    out[b * 3 + 2] = red[512] + b2[2];
  }
}

extern "C" void kernel_launch(void* const* d_in, const int* in_sizes, int n_in,
                              void* d_out, int out_size, void* d_ws, size_t ws_size,
                              hipStream_t stream) {
  const int*   seq1  = (const int*)  d_in[0];
  const int*   seq2  = (const int*)  d_in[1];
  const float* emb   = (const float*)d_in[2];
  const float* W_top = (const float*)d_in[3];
  const float* b_top = (const float*)d_in[4];
  const float* W_act = (const float*)d_in[5];
  const float* b_act = (const float*)d_in[6];
  const float* W1    = (const float*)d_in[7];
  const float* b1    = (const float*)d_in[8];
  const float* W2    = (const float*)d_in[9];
  const float* b2    = (const float*)d_in[10];
  float* out = (float*)d_out;
  float* ws  = (float*)d_ws;

  float* Eact  = ws + WS_EACT;
  float* delta = ws + WS_DELTA;
  float* diffb = ws + WS_DIFFB;
  float* fhid  = ws + WS_FHID;
  float* bigb  = ws + WS_BIG;   // fpart, then reused as part

  hipLaunchKernelGGL(k_fh_eact,     dim3(256 + 8000), dim3(256), 0, stream, emb, W_top, W_act, seq1, seq2, bigb, Eact);
  hipLaunchKernelGGL(k_ftanh_stats, dim3(512),        dim3(256), 0, stream, bigb, b_top, seq1, seq2, Eact, b_act, fhid, delta, diffb);
  hipLaunchKernelGGL(k_part,        dim3(1024),       dim3(256), 0, stream, fhid, W1, bigb);
  hipLaunchKernelGGL(k_clf_final,   dim3(129),        dim3(256), 0, stream, bigb, b1, W2, b2, delta, diffb, out);
}